// Round 1
// baseline (4518.325 us; speedup 1.0000x reference)
//
#include <hip/hip_runtime.h>
#include <math.h>

#define S_ 2048
#define D_ 1600
#define H_ 25

__device__ __forceinline__ float gelu_f(float x) {
    float x3 = x * x * x;
    return 0.5f * x * (1.0f + tanhf(0.7978845608028654f * (x + 0.044715f * x3)));
}

// ---------------- LayerNorm: one block per row (1600 floats = 400 float4) ----------------
__global__ __launch_bounds__(256) void ln_kernel(
    const float* __restrict__ x, const float* __restrict__ g,
    const float* __restrict__ bb, float* __restrict__ y)
{
    const int row = blockIdx.x;
    const float* xr = x + (size_t)row * D_;
    float* yr = y + (size_t)row * D_;
    const int tid = threadIdx.x;

    float4 a0 = ((const float4*)xr)[tid];
    float4 a1 = make_float4(0.f, 0.f, 0.f, 0.f);
    const bool has2 = tid < (D_ / 4 - 256);  // 144 extra float4
    if (has2) a1 = ((const float4*)xr)[256 + tid];

    float s  = a0.x + a0.y + a0.z + a0.w + a1.x + a1.y + a1.z + a1.w;
    float s2 = a0.x*a0.x + a0.y*a0.y + a0.z*a0.z + a0.w*a0.w
             + a1.x*a1.x + a1.y*a1.y + a1.z*a1.z + a1.w*a1.w;

    #pragma unroll
    for (int m = 32; m >= 1; m >>= 1) {
        s  += __shfl_xor(s,  m);
        s2 += __shfl_xor(s2, m);
    }
    __shared__ float red[8];
    const int lane = tid & 63, wv = tid >> 6;
    if (lane == 0) { red[wv] = s; red[4 + wv] = s2; }
    __syncthreads();
    if (tid == 0) {
        red[0] = red[0] + red[1] + red[2] + red[3];
        red[4] = red[4] + red[5] + red[6] + red[7];
    }
    __syncthreads();
    const float mean = red[0] * (1.f / D_);
    const float var  = red[4] * (1.f / D_) - mean * mean;
    const float rstd = rsqrtf(var + 1e-5f);

    float4 gv = ((const float4*)g)[tid];
    float4 bv = ((const float4*)bb)[tid];
    float4 o;
    o.x = (a0.x - mean) * rstd * gv.x + bv.x;
    o.y = (a0.y - mean) * rstd * gv.y + bv.y;
    o.z = (a0.z - mean) * rstd * gv.z + bv.z;
    o.w = (a0.w - mean) * rstd * gv.w + bv.w;
    ((float4*)yr)[tid] = o;
    if (has2) {
        gv = ((const float4*)g)[256 + tid];
        bv = ((const float4*)bb)[256 + tid];
        o.x = (a1.x - mean) * rstd * gv.x + bv.x;
        o.y = (a1.y - mean) * rstd * gv.y + bv.y;
        o.z = (a1.z - mean) * rstd * gv.z + bv.z;
        o.w = (a1.w - mean) * rstd * gv.w + bv.w;
        ((float4*)yr)[256 + tid] = o;
    }
}

// ---------------- fp32 SGEMM: C = A(MxK) @ B(KxN) + bias [+res | gelu] ----------------
// EPI: 0 = bias, 1 = bias + residual, 2 = bias + gelu
template<int EPI>
__global__ __launch_bounds__(256) void gemm_kernel(
    const float* __restrict__ A, const float* __restrict__ Bm,
    const float* __restrict__ bias, const float* __restrict__ R,
    float* __restrict__ C, int M, int N, int K)
{
    constexpr int BM = 128, BN = 128, BK = 16;
    __shared__ float As[BK][BM + 4];   // transposed A tile: As[k][m]
    __shared__ float Bs[BK][BN + 4];   // Bs[k][n]
    const int tid = threadIdx.x;
    const int bm = blockIdx.y * BM;
    const int bn = blockIdx.x * BN;
    const int tm = (tid >> 4) << 3;    // 16x16 thread grid, 8x8 per thread
    const int tn = (tid & 15) << 3;

    float acc[8][8];
    #pragma unroll
    for (int i = 0; i < 8; ++i)
        #pragma unroll
        for (int j = 0; j < 8; ++j) acc[i][j] = 0.f;

    for (int k0 = 0; k0 < K; k0 += BK) {
        #pragma unroll
        for (int l = 0; l < 2; ++l) {
            const int idx = l * 256 + tid;
            // A: 128 rows x 16 k  (4 float4 per row along k)
            const int ar = idx >> 2, akq = idx & 3;
            const float4 av = *(const float4*)(A + (size_t)(bm + ar) * K + k0 + akq * 4);
            As[akq * 4 + 0][ar] = av.x;
            As[akq * 4 + 1][ar] = av.y;
            As[akq * 4 + 2][ar] = av.z;
            As[akq * 4 + 3][ar] = av.w;
            // B: 16 rows x 128 n (32 float4 per row along n), guarded for N=4800 edge
            const int br = idx >> 5, bq = idx & 31;
            const int gn = bn + bq * 4;
            float4 bv;
            if (gn + 3 < N) {
                bv = *(const float4*)(Bm + (size_t)(k0 + br) * N + gn);
            } else {
                bv.x = (gn + 0 < N) ? Bm[(size_t)(k0 + br) * N + gn + 0] : 0.f;
                bv.y = (gn + 1 < N) ? Bm[(size_t)(k0 + br) * N + gn + 1] : 0.f;
                bv.z = (gn + 2 < N) ? Bm[(size_t)(k0 + br) * N + gn + 2] : 0.f;
                bv.w = (gn + 3 < N) ? Bm[(size_t)(k0 + br) * N + gn + 3] : 0.f;
            }
            *(float4*)(&Bs[br][bq * 4]) = bv;
        }
        __syncthreads();
        #pragma unroll
        for (int kk = 0; kk < BK; ++kk) {
            float a[8], b[8];
            *(float4*)(&a[0]) = *(const float4*)(&As[kk][tm]);
            *(float4*)(&a[4]) = *(const float4*)(&As[kk][tm + 4]);
            *(float4*)(&b[0]) = *(const float4*)(&Bs[kk][tn]);
            *(float4*)(&b[4]) = *(const float4*)(&Bs[kk][tn + 4]);
            #pragma unroll
            for (int i = 0; i < 8; ++i)
                #pragma unroll
                for (int j = 0; j < 8; ++j)
                    acc[i][j] = fmaf(a[i], b[j], acc[i][j]);
        }
        __syncthreads();
    }

    #pragma unroll
    for (int i = 0; i < 8; ++i) {
        const size_t row = bm + tm + i;
        #pragma unroll
        for (int jg = 0; jg < 2; ++jg) {
            const int col = bn + tn + jg * 4;
            if (col >= N) continue;   // N always multiple of 4 -> whole float4 valid
            const float4 bsv = *(const float4*)(bias + col);
            float4 o;
            o.x = acc[i][jg * 4 + 0] + bsv.x;
            o.y = acc[i][jg * 4 + 1] + bsv.y;
            o.z = acc[i][jg * 4 + 2] + bsv.z;
            o.w = acc[i][jg * 4 + 3] + bsv.w;
            if (EPI == 1) {
                const float4 rv = *(const float4*)(R + row * N + col);
                o.x += rv.x; o.y += rv.y; o.z += rv.z; o.w += rv.w;
            } else if (EPI == 2) {
                o.x = gelu_f(o.x); o.y = gelu_f(o.y);
                o.z = gelu_f(o.z); o.w = gelu_f(o.w);
            }
            *(float4*)(C + row * N + col) = o;
        }
    }
}

// ---------------- Flash attention, fp32, causal, head dim 64 ----------------
// Grid: (S/64, B*H). Block 256 = 16x16 thread grid, 4x4 register tile.
// Q,K stored transposed [ch][row] with XOR swizzle (conflict-free outer-product reads).
__global__ __launch_bounds__(256) void attn_kernel(
    const float* __restrict__ qkv, float* __restrict__ out)
{
    __shared__ float QsT[64 * 64];   // swizzled [c][r]
    __shared__ float KsT[64 * 64];   // swizzled [c][j]
    __shared__ float Vs[64 * 68];    // [j][c], pad 4
    __shared__ float PsT[64 * 68];   // [j][r], pad 4

    const int tid = threadIdx.x;
    const int g  = tid >> 4;   // row group 0..15  -> rows 4g..4g+3
    const int tx = tid & 15;   // col group        -> keys/cols 4tx..4tx+3
    const int q0 = blockIdx.x * 64;
    const int bh = blockIdx.y;
    const int bb = bh / H_;
    const int h  = bh % H_;
    const float* base = qkv + (size_t)bb * S_ * (3 * D_) + h * 64;

    // stage Q once (scaled by c^-0.5 = 0.125), transposed + swizzled
    #pragma unroll
    for (int l = 0; l < 4; ++l) {
        const int idx = l * 256 + tid;
        const int r = idx >> 4, qd = idx & 15;
        const float4 v = *(const float4*)(base + (size_t)(q0 + r) * (3 * D_) + qd * 4);
        const int rs = r ^ ((qd & 7) << 2);
        QsT[(4 * qd + 0) * 64 + rs] = v.x * 0.125f;
        QsT[(4 * qd + 1) * 64 + rs] = v.y * 0.125f;
        QsT[(4 * qd + 2) * 64 + rs] = v.z * 0.125f;
        QsT[(4 * qd + 3) * 64 + rs] = v.w * 0.125f;
    }

    float m_run[4], l_run[4], o[4][4];
    #pragma unroll
    for (int i = 0; i < 4; ++i) {
        m_run[i] = -INFINITY; l_run[i] = 0.f;
        #pragma unroll
        for (int u = 0; u < 4; ++u) o[i][u] = 0.f;
    }

    const int ntiles = q0 / 64 + 1;   // causal: only tiles with k0 <= q0
    for (int t = 0; t < ntiles; ++t) {
        const int k0 = t * 64;
        // stage K (transposed+swizzled) and V (row-major)
        #pragma unroll
        for (int l = 0; l < 4; ++l) {
            const int idx = l * 256 + tid;
            const int r = idx >> 4, qd = idx & 15;
            const float4 kv = *(const float4*)(base + D_ + (size_t)(k0 + r) * (3 * D_) + qd * 4);
            const int rs = r ^ ((qd & 7) << 2);
            KsT[(4 * qd + 0) * 64 + rs] = kv.x;
            KsT[(4 * qd + 1) * 64 + rs] = kv.y;
            KsT[(4 * qd + 2) * 64 + rs] = kv.z;
            KsT[(4 * qd + 3) * 64 + rs] = kv.w;
            const float4 vv = *(const float4*)(base + 2 * D_ + (size_t)(k0 + r) * (3 * D_) + qd * 4);
            *(float4*)(&Vs[r * 68 + qd * 4]) = vv;
        }
        __syncthreads();

        // scores: S = Q K^T via outer products over channel cc
        float s[4][4];
        #pragma unroll
        for (int i = 0; i < 4; ++i)
            #pragma unroll
            for (int j = 0; j < 4; ++j) s[i][j] = 0.f;
        #pragma unroll 8
        for (int cc = 0; cc < 64; ++cc) {
            const int swz = ((cc >> 2) & 7) << 2;
            float qa[4], ka[4];
            *(float4*)qa = *(const float4*)(&QsT[cc * 64 + ((4 * g) ^ swz)]);
            *(float4*)ka = *(const float4*)(&KsT[cc * 64 + ((4 * tx) ^ swz)]);
            #pragma unroll
            for (int i = 0; i < 4; ++i)
                #pragma unroll
                for (int j = 0; j < 4; ++j)
                    s[i][j] = fmaf(qa[i], ka[j], s[i][j]);
        }
        if (k0 == q0) {   // only the diagonal tile needs masking
            #pragma unroll
            for (int i = 0; i < 4; ++i)
                #pragma unroll
                for (int j = 0; j < 4; ++j)
                    if (k0 + 4 * tx + j > q0 + 4 * g + i) s[i][j] = -INFINITY;
        }

        // online softmax (row stats across the 16 lanes sharing g)
        float p[4][4];
        #pragma unroll
        for (int i = 0; i < 4; ++i) {
            float mt = fmaxf(fmaxf(s[i][0], s[i][1]), fmaxf(s[i][2], s[i][3]));
            #pragma unroll
            for (int m = 8; m >= 1; m >>= 1) mt = fmaxf(mt, __shfl_xor(mt, m, 16));
            const float mn = fmaxf(m_run[i], mt);
            const float sc = __expf(m_run[i] - mn);
            float ls = 0.f;
            #pragma unroll
            for (int j = 0; j < 4; ++j) { p[i][j] = __expf(s[i][j] - mn); ls += p[i][j]; }
            #pragma unroll
            for (int m = 8; m >= 1; m >>= 1) ls += __shfl_xor(ls, m, 16);
            l_run[i] = l_run[i] * sc + ls;
            m_run[i] = mn;
            #pragma unroll
            for (int u = 0; u < 4; ++u) o[i][u] *= sc;
        }

        // write P transposed: PsT[j][r]
        #pragma unroll
        for (int j = 0; j < 4; ++j) {
            float4 pv = make_float4(p[0][j], p[1][j], p[2][j], p[3][j]);
            *(float4*)(&PsT[(4 * tx + j) * 68 + 4 * g]) = pv;
        }
        __syncthreads();

        // O += P V
        #pragma unroll 8
        for (int j = 0; j < 64; ++j) {
            float pf[4], vf[4];
            *(float4*)pf = *(const float4*)(&PsT[j * 68 + 4 * g]);
            *(float4*)vf = *(const float4*)(&Vs[j * 68 + 4 * tx]);
            #pragma unroll
            for (int i = 0; i < 4; ++i)
                #pragma unroll
                for (int u = 0; u < 4; ++u)
                    o[i][u] = fmaf(pf[i], vf[u], o[i][u]);
        }
        __syncthreads();
    }

    float* op = out + (size_t)bb * S_ * D_ + h * 64;
    #pragma unroll
    for (int i = 0; i < 4; ++i) {
        const float inv = 1.f / l_run[i];
        float4 ov = make_float4(o[i][0] * inv, o[i][1] * inv, o[i][2] * inv, o[i][3] * inv);
        *(float4*)(op + (size_t)(q0 + 4 * g + i) * D_ + 4 * tx) = ov;
    }
}

extern "C" void kernel_launch(void* const* d_in, const int* in_sizes, int n_in,
                              void* d_out, int out_size, void* d_ws, size_t ws_size,
                              hipStream_t stream) {
    const float* x         = (const float*)d_in[0];
    const float* g1        = (const float*)d_in[1];
    const float* b1        = (const float*)d_in[2];
    const float* w_qkv     = (const float*)d_in[3];
    const float* bias_qkv  = (const float*)d_in[4];
    const float* w_proj    = (const float*)d_in[5];
    const float* bias_proj = (const float*)d_in[6];
    const float* g2        = (const float*)d_in[7];
    const float* b2        = (const float*)d_in[8];
    const float* w_fc      = (const float*)d_in[9];
    const float* bias_fc   = (const float*)d_in[10];
    const float* w_out     = (const float*)d_in[11];
    const float* bias_out  = (const float*)d_in[12];
    float* out = (float*)d_out;
    float* ws  = (float*)d_ws;

    // workspace layout (floats):
    // [0, 6.55M)      xn / xn2
    // [6.55M, 26.2M)  qkv            \  hdn (26.2M floats) overlays qkv+att
    // [26.2M, 32.8M)  att            /  after both are dead
    // [32.8M, 39.3M)  x1
    float* xn  = ws;
    float* qkv = ws + 6553600;
    float* att = ws + 26214400;
    float* x1  = ws + 32768000;
    float* hdn = ws + 6553600;

    dim3 blk(256);
    // 1. LN1
    ln_kernel<<<4096, blk, 0, stream>>>(x, g1, b1, xn);
    // 2. qkv = xn @ w_qkv + bias   (M=4096, N=4800, K=1600)
    gemm_kernel<0><<<dim3(38, 32), blk, 0, stream>>>(xn, w_qkv, bias_qkv, nullptr, qkv, 4096, 4800, 1600);
    // 3. attention
    attn_kernel<<<dim3(32, 50), blk, 0, stream>>>(qkv, att);
    // 4. x1 = att @ w_proj + bias + x    (N=1600, K=1600)
    gemm_kernel<1><<<dim3(13, 32), blk, 0, stream>>>(att, w_proj, bias_proj, x, x1, 4096, 1600, 1600);
    // 5. LN2
    ln_kernel<<<4096, blk, 0, stream>>>(x1, g2, b2, xn);
    // 6. hdn = gelu(xn @ w_fc + bias)    (N=6400, K=1600)
    gemm_kernel<2><<<dim3(50, 32), blk, 0, stream>>>(xn, w_fc, bias_fc, nullptr, hdn, 4096, 6400, 1600);
    // 7. out = hdn @ w_out + bias + x1   (N=1600, K=6400)
    gemm_kernel<1><<<dim3(13, 32), blk, 0, stream>>>(hdn, w_out, bias_out, x1, out, 4096, 1600, 6400);
}

// Round 4
// 2216.414 us; speedup vs baseline: 2.0386x; 2.0386x over previous
//
#include <hip/hip_runtime.h>
#include <math.h>

#define S_ 2048
#define D_ 1600
#define H_ 25

typedef unsigned short u16;
typedef __attribute__((ext_vector_type(8))) short short8;
typedef __attribute__((ext_vector_type(16))) float f32x16;

static __device__ __forceinline__ u16 f2bf(float f) {
    unsigned u = __float_as_uint(f);
    u += 0x7fffu + ((u >> 16) & 1u);
    return (u16)(u >> 16);
}
static __device__ __forceinline__ float bf2f(u16 h) {
    return __uint_as_float(((unsigned)h) << 16);
}

__device__ __forceinline__ float gelu_f(float x) {
    float x3 = x * x * x;
    return 0.5f * x * (1.0f + tanhf(0.7978845608028654f * (x + 0.044715f * x3)));
}

// ---------------- weight split+transpose: W[K][ldW] fp32 -> WT_h/WT_l [Np][K] bf16 ----------------
// grid (Np/32, K/32); cols n0 >= N (pad rows of the transposed output) are zero-filled.
__global__ __launch_bounds__(256) void wsplit_kernel(
    const float* __restrict__ W, int ldW, u16* __restrict__ Th, u16* __restrict__ Tl,
    int K, int N)
{
    __shared__ __align__(16) float tile[32][33];
    const int tid = threadIdx.x;
    const int n0 = blockIdx.x * 32;
    const int k0 = blockIdx.y * 32;
    const int r = tid >> 3, cq = tid & 7;
    if (n0 < N) {
        const float4 v = *(const float4*)(W + (size_t)(k0 + r) * ldW + n0 + cq * 4);
        tile[r][cq * 4 + 0] = v.x; tile[r][cq * 4 + 1] = v.y;
        tile[r][cq * 4 + 2] = v.z; tile[r][cq * 4 + 3] = v.w;
    }
    __syncthreads();
    const int n = tid >> 3, kq = tid & 7;
    ushort4 hv = make_ushort4(0, 0, 0, 0), lv = make_ushort4(0, 0, 0, 0);
    if (n0 < N) {
        float f0 = tile[kq * 4 + 0][n], f1 = tile[kq * 4 + 1][n];
        float f2 = tile[kq * 4 + 2][n], f3 = tile[kq * 4 + 3][n];
        u16 h0 = f2bf(f0), h1 = f2bf(f1), h2 = f2bf(f2), h3 = f2bf(f3);
        hv = make_ushort4(h0, h1, h2, h3);
        lv = make_ushort4(f2bf(f0 - bf2f(h0)), f2bf(f1 - bf2f(h1)),
                          f2bf(f2 - bf2f(h2)), f2bf(f3 - bf2f(h3)));
    }
    const size_t o = (size_t)(n0 + n) * K + k0 + kq * 4;
    *(ushort4*)(Th + o) = hv;
    *(ushort4*)(Tl + o) = lv;
}

// ---------------- LayerNorm -> split bf16 hi/lo outputs ----------------
__global__ __launch_bounds__(256) void ln_split_kernel(
    const float* __restrict__ x, const float* __restrict__ g,
    const float* __restrict__ bb, u16* __restrict__ yh, u16* __restrict__ yl)
{
    const int row = blockIdx.x;
    const float* xr = x + (size_t)row * D_;
    const int tid = threadIdx.x;

    float4 a0 = ((const float4*)xr)[tid];
    float4 a1 = make_float4(0.f, 0.f, 0.f, 0.f);
    const bool has2 = tid < (D_ / 4 - 256);
    if (has2) a1 = ((const float4*)xr)[256 + tid];

    float s  = a0.x + a0.y + a0.z + a0.w + a1.x + a1.y + a1.z + a1.w;
    float s2 = a0.x*a0.x + a0.y*a0.y + a0.z*a0.z + a0.w*a0.w
             + a1.x*a1.x + a1.y*a1.y + a1.z*a1.z + a1.w*a1.w;

    #pragma unroll
    for (int m = 32; m >= 1; m >>= 1) {
        s  += __shfl_xor(s,  m);
        s2 += __shfl_xor(s2, m);
    }
    __shared__ float red[8];
    const int lane = tid & 63, wv = tid >> 6;
    if (lane == 0) { red[wv] = s; red[4 + wv] = s2; }
    __syncthreads();
    if (tid == 0) {
        red[0] = red[0] + red[1] + red[2] + red[3];
        red[4] = red[4] + red[5] + red[6] + red[7];
    }
    __syncthreads();
    const float mean = red[0] * (1.f / D_);
    const float var  = red[4] * (1.f / D_) - mean * mean;
    const float rstd = rsqrtf(var + 1e-5f);

    u16* yhr = yh + (size_t)row * D_;
    u16* ylr = yl + (size_t)row * D_;

    float4 gv = ((const float4*)g)[tid];
    float4 bv = ((const float4*)bb)[tid];
    float o0 = (a0.x - mean) * rstd * gv.x + bv.x;
    float o1 = (a0.y - mean) * rstd * gv.y + bv.y;
    float o2 = (a0.z - mean) * rstd * gv.z + bv.z;
    float o3 = (a0.w - mean) * rstd * gv.w + bv.w;
    u16 h0 = f2bf(o0), h1 = f2bf(o1), h2 = f2bf(o2), h3 = f2bf(o3);
    ((ushort4*)yhr)[tid] = make_ushort4(h0, h1, h2, h3);
    ((ushort4*)ylr)[tid] = make_ushort4(f2bf(o0 - bf2f(h0)), f2bf(o1 - bf2f(h1)),
                                        f2bf(o2 - bf2f(h2)), f2bf(o3 - bf2f(h3)));
    if (has2) {
        gv = ((const float4*)g)[256 + tid];
        bv = ((const float4*)bb)[256 + tid];
        o0 = (a1.x - mean) * rstd * gv.x + bv.x;
        o1 = (a1.y - mean) * rstd * gv.y + bv.y;
        o2 = (a1.z - mean) * rstd * gv.z + bv.z;
        o3 = (a1.w - mean) * rstd * gv.w + bv.w;
        h0 = f2bf(o0); h1 = f2bf(o1); h2 = f2bf(o2); h3 = f2bf(o3);
        ((ushort4*)yhr)[256 + tid] = make_ushort4(h0, h1, h2, h3);
        ((ushort4*)ylr)[256 + tid] = make_ushort4(f2bf(o0 - bf2f(h0)), f2bf(o1 - bf2f(h1)),
                                                  f2bf(o2 - bf2f(h2)), f2bf(o3 - bf2f(h3)));
    }
}

// ---------------- bf16x3 MFMA GEMM: C = Ah*Bh + Ah*Bl + Al*Bh (+bias, epilogues) ----------------
// A: AMODE 0 = dense [M][K] bf16 (row stride lda bytes); AMODE 1 = qkv Q-slot layout
//    (row stride lda bytes, k -> (k/64)*256 + (k%64)*2 byte offset; Alb pre-offset +128).
// B: dense [Np][K] bf16 pair (B^T of the math).
// EPI: 0 = C+bias; 1 = C+bias+R; 2 = gelu -> split Ch/Cl; 3 = C += acc (accumulate, no bias).
template<int EPI, int AMODE>
__global__ __launch_bounds__(256, 2) void mgemm(
    const char* __restrict__ Ahb, const char* __restrict__ Alb, long lda,
    const u16* __restrict__ Bh, const u16* __restrict__ Bl,
    const float* __restrict__ bias, const float* __restrict__ R,
    float* __restrict__ C, u16* __restrict__ Ch, u16* __restrict__ Cl,
    int ldc, int N, int K)
{
    __shared__ __align__(16) u16 sm[4][4096];   // Ah, Al, Bh, Bl tiles: 128 rows x 32 k
    const int tid = threadIdx.x;

    // XCD-bijective swizzle (all grids have nwg % 8 == 0)
    const int gx = gridDim.x;
    const int nwg = gx * (int)gridDim.y;
    const int bid0 = blockIdx.y * gx + blockIdx.x;
    const int cpx = nwg >> 3;
    const int bid = (bid0 & 7) * cpx + (bid0 >> 3);
    const int bn = (bid % gx) * 128;
    const int bm = (bid / gx) * 128;

    const int lrow  = tid & 31;
    const int lhalf = (tid >> 5) & 1;
    const int wid   = tid >> 6;
    const int wr = (wid >> 1) * 64;
    const int wc = (wid & 1) * 64;

    f32x16 acc[2][2];
    #pragma unroll
    for (int mt = 0; mt < 2; ++mt)
        #pragma unroll
        for (int nt = 0; nt < 2; ++nt)
            #pragma unroll
            for (int i = 0; i < 16; ++i) acc[mt][nt][i] = 0.f;

    for (int k0 = 0; k0 < K; k0 += 32) {
        // stage 4 tiles; LDS dest linear (idx*16B), source chunk pre-swizzled
        #pragma unroll
        for (int p = 0; p < 2; ++p) {
            const int idx = p * 256 + tid;
            const int r = idx >> 2, pch = idx & 3;
            const int c = pch ^ ((r >> 1) & 3);
            const int ke = k0 + c * 8;
            const size_t ra = (size_t)(bm + r) * lda;
            const size_t ka = (AMODE == 0) ? (size_t)ke * 2
                                           : (size_t)(((ke >> 6) << 8) + ((ke & 63) << 1));
            __builtin_amdgcn_global_load_lds((const u16*)(Ahb + ra + ka), &sm[0][idx * 8], 16, 0, 0);
            __builtin_amdgcn_global_load_lds((const u16*)(Alb + ra + ka), &sm[1][idx * 8], 16, 0, 0);
            const size_t rb = (size_t)(bn + r) * K + ke;
            __builtin_amdgcn_global_load_lds(Bh + rb, &sm[2][idx * 8], 16, 0, 0);
            __builtin_amdgcn_global_load_lds(Bl + rb, &sm[3][idx * 8], 16, 0, 0);
        }
        __syncthreads();
        #pragma unroll
        for (int kc = 0; kc < 2; ++kc) {
            short8 fa_h[2], fa_l[2], fb_h[2], fb_l[2];
            const int ch = kc * 2 + lhalf;
            #pragma unroll
            for (int mt = 0; mt < 2; ++mt) {
                const int rr = wr + mt * 32 + lrow;
                const int off = rr * 32 + ((ch ^ ((rr >> 1) & 3)) << 3);
                fa_h[mt] = *(const short8*)&sm[0][off];
                fa_l[mt] = *(const short8*)&sm[1][off];
            }
            #pragma unroll
            for (int nt = 0; nt < 2; ++nt) {
                const int rr = wc + nt * 32 + lrow;
                const int off = rr * 32 + ((ch ^ ((rr >> 1) & 3)) << 3);
                fb_h[nt] = *(const short8*)&sm[2][off];
                fb_l[nt] = *(const short8*)&sm[3][off];
            }
            #pragma unroll
            for (int mt = 0; mt < 2; ++mt)
                #pragma unroll
                for (int nt = 0; nt < 2; ++nt) {
                    acc[mt][nt] = __builtin_amdgcn_mfma_f32_32x32x16_bf16(fa_h[mt], fb_h[nt], acc[mt][nt], 0, 0, 0);
                    acc[mt][nt] = __builtin_amdgcn_mfma_f32_32x32x16_bf16(fa_h[mt], fb_l[nt], acc[mt][nt], 0, 0, 0);
                    acc[mt][nt] = __builtin_amdgcn_mfma_f32_32x32x16_bf16(fa_l[mt], fb_h[nt], acc[mt][nt], 0, 0, 0);
                }
        }
        __syncthreads();
    }

    // epilogue: C/D layout col = lane&31, row = (i&3) + 8*(i>>2) + 4*(lane>>5)
    #pragma unroll
    for (int mt = 0; mt < 2; ++mt) {
        #pragma unroll
        for (int nt = 0; nt < 2; ++nt) {
            const int col = bn + wc + nt * 32 + lrow;
            if (col < N) {
                const float bsv = (EPI == 3) ? 0.f : bias[col];
                #pragma unroll
                for (int i = 0; i < 16; ++i) {
                    const int row = bm + wr + mt * 32 + (i & 3) + 8 * (i >> 2) + 4 * lhalf;
                    float v = acc[mt][nt][i] + bsv;
                    const size_t o = (size_t)row * ldc + col;
                    if (EPI == 0) {
                        C[o] = v;
                    } else if (EPI == 1) {
                        C[o] = v + R[o];
                    } else if (EPI == 3) {
                        C[o] = C[o] + v;
                    } else {
                        const float gv = gelu_f(v);
                        const u16 h = f2bf(gv);
                        Ch[o] = h;
                        Cl[o] = f2bf(gv - bf2f(h));
                    }
                }
            }
        }
    }
}

// ---------------- Flash attention, fp32, causal, head dim 64 ----------------
// Output written IN-PLACE into the Q-slot of qkv as split bf16:
// per row s, head h: u16* ph = (u16*)(qkv + row_off + h*64); ph[0..63]=hi, ph[64..127]=lo.
// Race-free: each (row, head) Q-slot is read only by the block that writes it,
// reads (LDS staging) precede writes within that block; K/V slots untouched.
__global__ __launch_bounds__(256) void attn_kernel(float* __restrict__ qkv)
{
    __shared__ __align__(16) float QsT[64 * 64];
    __shared__ __align__(16) float KsT[64 * 64];
    __shared__ __align__(16) float Vs[64 * 68];
    __shared__ __align__(16) float PsT[64 * 68];

    const int tid = threadIdx.x;
    const int g  = tid >> 4;
    const int tx = tid & 15;
    const int q0 = blockIdx.x * 64;
    const int bh = blockIdx.y;
    const int bb = bh / H_;
    const int h  = bh % H_;
    float* base = qkv + (size_t)bb * S_ * (3 * D_) + h * 64;

    #pragma unroll
    for (int l = 0; l < 4; ++l) {
        const int idx = l * 256 + tid;
        const int r = idx >> 4, qd = idx & 15;
        const float4 v = *(const float4*)(base + (size_t)(q0 + r) * (3 * D_) + qd * 4);
        const int rs = r ^ ((qd & 7) << 2);
        QsT[(4 * qd + 0) * 64 + rs] = v.x * 0.125f;
        QsT[(4 * qd + 1) * 64 + rs] = v.y * 0.125f;
        QsT[(4 * qd + 2) * 64 + rs] = v.z * 0.125f;
        QsT[(4 * qd + 3) * 64 + rs] = v.w * 0.125f;
    }

    float m_run[4], l_run[4], o[4][4];
    #pragma unroll
    for (int i = 0; i < 4; ++i) {
        m_run[i] = -INFINITY; l_run[i] = 0.f;
        #pragma unroll
        for (int u = 0; u < 4; ++u) o[i][u] = 0.f;
    }

    const int ntiles = q0 / 64 + 1;
    for (int t = 0; t < ntiles; ++t) {
        const int k0 = t * 64;
        #pragma unroll
        for (int l = 0; l < 4; ++l) {
            const int idx = l * 256 + tid;
            const int r = idx >> 4, qd = idx & 15;
            const float4 kv = *(const float4*)(base + D_ + (size_t)(k0 + r) * (3 * D_) + qd * 4);
            const int rs = r ^ ((qd & 7) << 2);
            KsT[(4 * qd + 0) * 64 + rs] = kv.x;
            KsT[(4 * qd + 1) * 64 + rs] = kv.y;
            KsT[(4 * qd + 2) * 64 + rs] = kv.z;
            KsT[(4 * qd + 3) * 64 + rs] = kv.w;
            const float4 vv = *(const float4*)(base + 2 * D_ + (size_t)(k0 + r) * (3 * D_) + qd * 4);
            *(float4*)(&Vs[r * 68 + qd * 4]) = vv;
        }
        __syncthreads();

        float s[4][4];
        #pragma unroll
        for (int i = 0; i < 4; ++i)
            #pragma unroll
            for (int j = 0; j < 4; ++j) s[i][j] = 0.f;
        #pragma unroll 8
        for (int cc = 0; cc < 64; ++cc) {
            const int swz = ((cc >> 2) & 7) << 2;
            float qa[4], ka[4];
            *(float4*)qa = *(const float4*)(&QsT[cc * 64 + ((4 * g) ^ swz)]);
            *(float4*)ka = *(const float4*)(&KsT[cc * 64 + ((4 * tx) ^ swz)]);
            #pragma unroll
            for (int i = 0; i < 4; ++i)
                #pragma unroll
                for (int j = 0; j < 4; ++j)
                    s[i][j] = fmaf(qa[i], ka[j], s[i][j]);
        }
        if (k0 == q0) {
            #pragma unroll
            for (int i = 0; i < 4; ++i)
                #pragma unroll
                for (int j = 0; j < 4; ++j)
                    if (k0 + 4 * tx + j > q0 + 4 * g + i) s[i][j] = -INFINITY;
        }

        float p[4][4];
        #pragma unroll
        for (int i = 0; i < 4; ++i) {
            float mt = fmaxf(fmaxf(s[i][0], s[i][1]), fmaxf(s[i][2], s[i][3]));
            #pragma unroll
            for (int m = 8; m >= 1; m >>= 1) mt = fmaxf(mt, __shfl_xor(mt, m, 16));
            const float mn = fmaxf(m_run[i], mt);
            const float sc = __expf(m_run[i] - mn);
            float ls = 0.f;
            #pragma unroll
            for (int j = 0; j < 4; ++j) { p[i][j] = __expf(s[i][j] - mn); ls += p[i][j]; }
            #pragma unroll
            for (int m = 8; m >= 1; m >>= 1) ls += __shfl_xor(ls, m, 16);
            l_run[i] = l_run[i] * sc + ls;
            m_run[i] = mn;
            #pragma unroll
            for (int u = 0; u < 4; ++u) o[i][u] *= sc;
        }

        #pragma unroll
        for (int j = 0; j < 4; ++j) {
            float4 pv = make_float4(p[0][j], p[1][j], p[2][j], p[3][j]);
            *(float4*)(&PsT[(4 * tx + j) * 68 + 4 * g]) = pv;
        }
        __syncthreads();

        #pragma unroll 8
        for (int j = 0; j < 64; ++j) {
            float pf[4], vf[4];
            *(float4*)pf = *(const float4*)(&PsT[j * 68 + 4 * g]);
            *(float4*)vf = *(const float4*)(&Vs[j * 68 + 4 * tx]);
            #pragma unroll
            for (int i = 0; i < 4; ++i)
                #pragma unroll
                for (int u = 0; u < 4; ++u)
                    o[i][u] = fmaf(pf[i], vf[u], o[i][u]);
        }
        __syncthreads();
    }

    // write split bf16 output into the Q-slot
    #pragma unroll
    for (int i = 0; i < 4; ++i) {
        const float inv = 1.f / l_run[i];
        float o0 = o[i][0] * inv, o1 = o[i][1] * inv, o2 = o[i][2] * inv, o3 = o[i][3] * inv;
        u16 h0 = f2bf(o0), h1 = f2bf(o1), h2 = f2bf(o2), h3 = f2bf(o3);
        u16* ph = (u16*)(base + (size_t)(q0 + 4 * g + i) * (3 * D_));
        *(ushort4*)(ph + 4 * tx)      = make_ushort4(h0, h1, h2, h3);
        *(ushort4*)(ph + 64 + 4 * tx) = make_ushort4(f2bf(o0 - bf2f(h0)), f2bf(o1 - bf2f(h1)),
                                                     f2bf(o2 - bf2f(h2)), f2bf(o3 - bf2f(h3)));
    }
}

extern "C" void kernel_launch(void* const* d_in, const int* in_sizes, int n_in,
                              void* d_out, int out_size, void* d_ws, size_t ws_size,
                              hipStream_t stream) {
    const float* x         = (const float*)d_in[0];
    const float* g1        = (const float*)d_in[1];
    const float* b1        = (const float*)d_in[2];
    const float* w_qkv     = (const float*)d_in[3];
    const float* bias_qkv  = (const float*)d_in[4];
    const float* w_proj    = (const float*)d_in[5];
    const float* bias_proj = (const float*)d_in[6];
    const float* g2        = (const float*)d_in[7];
    const float* b2        = (const float*)d_in[8];
    const float* w_fc      = (const float*)d_in[9];
    const float* bias_fc   = (const float*)d_in[10];
    const float* w_out     = (const float*)d_in[11];
    const float* bias_out  = (const float*)d_in[12];
    float* out = (float*)d_out;
    char* W = (char*)d_ws;

    // workspace layout (bytes), peak 152,371,200 (< 157,286,400 proven safe in round 1):
    u16*   xnh  = (u16*)  (W + 0);           // 13,107,200
    u16*   xnl  = (u16*)  (W + 13107200);    // 13,107,200
    float* x1   = (float*)(W + 26214400);    // 26,214,400
    float* qkv  = (float*)(W + 52428800);    // 78,643,200 (f32 [2][2048][4800])
    u16*   hdnh = (u16*)  (W + 52428800);    // 26,214,400 (reuse qkv region, [4096][3200])
    u16*   hdnl = (u16*)  (W + 78643200);    // 26,214,400
    u16*   wh   = (u16*)  (W + 131072000);   // 10,649,600 (shared weight-split region, hi)
    u16*   wl   = (u16*)  (W + 141721600);   // 10,649,600 (lo)  -> ends 152,371,200

    dim3 blk(256);

    // 1. LN1 -> split
    ln_split_kernel<<<4096, blk, 0, stream>>>(x, g1, b1, xnh, xnl);

    // 2. qkv = xn @ w_qkv + bias, in two column-halves (N=2400 each, padded to 2432)
    for (int ci = 0; ci < 2; ++ci) {
        wsplit_kernel<<<dim3(76, 50), blk, 0, stream>>>(w_qkv + ci * 2400, 4800, wh, wl, 1600, 2400);
        mgemm<0, 0><<<dim3(19, 32), blk, 0, stream>>>(
            (const char*)xnh, (const char*)xnl, 3200L, wh, wl,
            bias_qkv + ci * 2400, nullptr, qkv + ci * 2400, nullptr, nullptr,
            4800, 2400, 1600);
    }

    // 3. attention (reads fp32 qkv; writes split-bf16 output into Q-slots in place)
    attn_kernel<<<dim3(32, 50), blk, 0, stream>>>(qkv);

    // 4. x1 = att @ w_proj + bias + x   (A from Q-slots, AMODE=1)
    wsplit_kernel<<<dim3(52, 50), blk, 0, stream>>>(w_proj, 1600, wh, wl, 1600, 1600);
    mgemm<1, 1><<<dim3(13, 32), blk, 0, stream>>>(
        (const char*)qkv, (const char*)qkv + 128, 19200L, wh, wl,
        bias_proj, x, x1, nullptr, nullptr, 1600, 1600, 1600);

    // 5. LN2 -> split
    ln_split_kernel<<<4096, blk, 0, stream>>>(x1, g2, b2, xnh, xnl);

    // 6+7. MLP in two K-chunks of 3200: fc chunk -> hdn, then out-chunk accumulates
    for (int ci = 0; ci < 2; ++ci) {
        // hdn_ci = gelu(xn @ w_fc[:, ci*3200 : +3200] + bias) -> split (N=3200, exact tiles)
        wsplit_kernel<<<dim3(100, 50), blk, 0, stream>>>(w_fc + ci * 3200, 6400, wh, wl, 1600, 3200);
        mgemm<2, 0><<<dim3(25, 32), blk, 0, stream>>>(
            (const char*)xnh, (const char*)xnl, 3200L, wh, wl,
            bias_fc + ci * 3200, nullptr, nullptr, hdnh, hdnl,
            3200, 3200, 1600);
        // out (+)= hdn_ci @ w_out[ci*3200 : +3200, :]  (pass 0: +bias+x1; pass 1: accumulate)
        wsplit_kernel<<<dim3(52, 100), blk, 0, stream>>>(w_out + (size_t)ci * 3200 * 1600, 1600, wh, wl, 3200, 1600);
        if (ci == 0) {
            mgemm<1, 0><<<dim3(13, 32), blk, 0, stream>>>(
                (const char*)hdnh, (const char*)hdnl, 6400L, wh, wl,
                bias_out, x1, out, nullptr, nullptr, 1600, 1600, 3200);
        } else {
            mgemm<3, 0><<<dim3(13, 32), blk, 0, stream>>>(
                (const char*)hdnh, (const char*)hdnl, 6400L, wh, wl,
                bias_out, nullptr, out, nullptr, nullptr, 1600, 1600, 3200);
        }
    }
}

// Round 5
// 1441.001 us; speedup vs baseline: 3.1355x; 1.5381x over previous
//
#include <hip/hip_runtime.h>
#include <math.h>

#define S_ 2048
#define D_ 1600
#define H_ 25

typedef unsigned short u16;
typedef __attribute__((ext_vector_type(8))) short short8;
typedef __attribute__((ext_vector_type(16))) float f32x16;

static __device__ __forceinline__ u16 f2bf(float f) {
    unsigned u = __float_as_uint(f);
    u += 0x7fffu + ((u >> 16) & 1u);
    return (u16)(u >> 16);
}
static __device__ __forceinline__ float bf2f(u16 h) {
    return __uint_as_float(((unsigned)h) << 16);
}
static __device__ __forceinline__ void split2(float f, u16& hi, u16& lo) {
    hi = f2bf(f);
    lo = f2bf(f - bf2f(hi));
}

__device__ __forceinline__ float gelu_f(float x) {
    float x3 = x * x * x;
    return 0.5f * x * (1.0f + tanhf(0.7978845608028654f * (x + 0.044715f * x3)));
}

// chunk-XOR swizzle for bf16 tiles with 64-elem (128 B) rows: 16B chunk ^= row&7
__device__ __forceinline__ int swz(int row, int col) {
    return row * 64 + ((((col >> 3) ^ row) & 7) << 3) + (col & 7);
}

// ---------------- weight split+transpose: W[K][ldW] fp32 -> WT_h/WT_l [Np][K] bf16 ----------------
__global__ __launch_bounds__(256) void wsplit_kernel(
    const float* __restrict__ W, int ldW, u16* __restrict__ Th, u16* __restrict__ Tl,
    int K, int N)
{
    __shared__ __align__(16) float tile[32][33];
    const int tid = threadIdx.x;
    const int n0 = blockIdx.x * 32;
    const int k0 = blockIdx.y * 32;
    const int r = tid >> 3, cq = tid & 7;
    if (n0 < N) {
        const float4 v = *(const float4*)(W + (size_t)(k0 + r) * ldW + n0 + cq * 4);
        tile[r][cq * 4 + 0] = v.x; tile[r][cq * 4 + 1] = v.y;
        tile[r][cq * 4 + 2] = v.z; tile[r][cq * 4 + 3] = v.w;
    }
    __syncthreads();
    const int n = tid >> 3, kq = tid & 7;
    ushort4 hv = make_ushort4(0, 0, 0, 0), lv = make_ushort4(0, 0, 0, 0);
    if (n0 < N) {
        float f0 = tile[kq * 4 + 0][n], f1 = tile[kq * 4 + 1][n];
        float f2 = tile[kq * 4 + 2][n], f3 = tile[kq * 4 + 3][n];
        split2(f0, hv.x, lv.x); split2(f1, hv.y, lv.y);
        split2(f2, hv.z, lv.z); split2(f3, hv.w, lv.w);
    }
    const size_t o = (size_t)(n0 + n) * K + k0 + kq * 4;
    *(ushort4*)(Th + o) = hv;
    *(ushort4*)(Tl + o) = lv;
}

// ---------------- LayerNorm -> split bf16 hi/lo outputs ----------------
__global__ __launch_bounds__(256) void ln_split_kernel(
    const float* __restrict__ x, const float* __restrict__ g,
    const float* __restrict__ bb, u16* __restrict__ yh, u16* __restrict__ yl)
{
    const int row = blockIdx.x;
    const float* xr = x + (size_t)row * D_;
    const int tid = threadIdx.x;

    float4 a0 = ((const float4*)xr)[tid];
    float4 a1 = make_float4(0.f, 0.f, 0.f, 0.f);
    const bool has2 = tid < (D_ / 4 - 256);
    if (has2) a1 = ((const float4*)xr)[256 + tid];

    float s  = a0.x + a0.y + a0.z + a0.w + a1.x + a1.y + a1.z + a1.w;
    float s2 = a0.x*a0.x + a0.y*a0.y + a0.z*a0.z + a0.w*a0.w
             + a1.x*a1.x + a1.y*a1.y + a1.z*a1.z + a1.w*a1.w;

    #pragma unroll
    for (int m = 32; m >= 1; m >>= 1) {
        s  += __shfl_xor(s,  m);
        s2 += __shfl_xor(s2, m);
    }
    __shared__ float red[8];
    const int lane = tid & 63, wv = tid >> 6;
    if (lane == 0) { red[wv] = s; red[4 + wv] = s2; }
    __syncthreads();
    if (tid == 0) {
        red[0] = red[0] + red[1] + red[2] + red[3];
        red[4] = red[4] + red[5] + red[6] + red[7];
    }
    __syncthreads();
    const float mean = red[0] * (1.f / D_);
    const float var  = red[4] * (1.f / D_) - mean * mean;
    const float rstd = rsqrtf(var + 1e-5f);

    u16* yhr = yh + (size_t)row * D_;
    u16* ylr = yl + (size_t)row * D_;

    float4 gv = ((const float4*)g)[tid];
    float4 bv = ((const float4*)bb)[tid];
    ushort4 hq, lq;
    split2((a0.x - mean) * rstd * gv.x + bv.x, hq.x, lq.x);
    split2((a0.y - mean) * rstd * gv.y + bv.y, hq.y, lq.y);
    split2((a0.z - mean) * rstd * gv.z + bv.z, hq.z, lq.z);
    split2((a0.w - mean) * rstd * gv.w + bv.w, hq.w, lq.w);
    ((ushort4*)yhr)[tid] = hq;
    ((ushort4*)ylr)[tid] = lq;
    if (has2) {
        gv = ((const float4*)g)[256 + tid];
        bv = ((const float4*)bb)[256 + tid];
        split2((a1.x - mean) * rstd * gv.x + bv.x, hq.x, lq.x);
        split2((a1.y - mean) * rstd * gv.y + bv.y, hq.y, lq.y);
        split2((a1.z - mean) * rstd * gv.z + bv.z, hq.z, lq.z);
        split2((a1.w - mean) * rstd * gv.w + bv.w, hq.w, lq.w);
        ((ushort4*)yhr)[256 + tid] = hq;
        ((ushort4*)ylr)[256 + tid] = lq;
    }
}

// ---------------- bf16x3 MFMA GEMM: C = Ah*Bh + Ah*Bl + Al*Bh (+bias, epilogues) ----------------
// AMODE 0 = dense [M][K] bf16 (row stride lda bytes); AMODE 1 = qkv Q-slot layout.
// EPI: 0 = C+bias; 1 = C+bias+R; 2 = gelu -> split Ch/Cl; 3 = C += acc.
template<int EPI, int AMODE>
__global__ __launch_bounds__(256, 2) void mgemm(
    const char* __restrict__ Ahb, const char* __restrict__ Alb, long lda,
    const u16* __restrict__ Bh, const u16* __restrict__ Bl,
    const float* __restrict__ bias, const float* __restrict__ R,
    float* __restrict__ C, u16* __restrict__ Ch, u16* __restrict__ Cl,
    int ldc, int N, int K)
{
    __shared__ __align__(16) u16 sm[4][4096];
    const int tid = threadIdx.x;

    const int gx = gridDim.x;
    const int nwg = gx * (int)gridDim.y;
    const int bid0 = blockIdx.y * gx + blockIdx.x;
    const int cpx = nwg >> 3;
    const int bid = (bid0 & 7) * cpx + (bid0 >> 3);
    const int bn = (bid % gx) * 128;
    const int bm = (bid / gx) * 128;

    const int lrow  = tid & 31;
    const int lhalf = (tid >> 5) & 1;
    const int wid   = tid >> 6;
    const int wr = (wid >> 1) * 64;
    const int wc = (wid & 1) * 64;

    f32x16 acc[2][2];
    #pragma unroll
    for (int mt = 0; mt < 2; ++mt)
        #pragma unroll
        for (int nt = 0; nt < 2; ++nt)
            #pragma unroll
            for (int i = 0; i < 16; ++i) acc[mt][nt][i] = 0.f;

    for (int k0 = 0; k0 < K; k0 += 32) {
        #pragma unroll
        for (int p = 0; p < 2; ++p) {
            const int idx = p * 256 + tid;
            const int r = idx >> 2, pch = idx & 3;
            const int c = pch ^ ((r >> 1) & 3);
            const int ke = k0 + c * 8;
            const size_t ra = (size_t)(bm + r) * lda;
            const size_t ka = (AMODE == 0) ? (size_t)ke * 2
                                           : (size_t)(((ke >> 6) << 8) + ((ke & 63) << 1));
            __builtin_amdgcn_global_load_lds((const u16*)(Ahb + ra + ka), &sm[0][idx * 8], 16, 0, 0);
            __builtin_amdgcn_global_load_lds((const u16*)(Alb + ra + ka), &sm[1][idx * 8], 16, 0, 0);
            const size_t rb = (size_t)(bn + r) * K + ke;
            __builtin_amdgcn_global_load_lds(Bh + rb, &sm[2][idx * 8], 16, 0, 0);
            __builtin_amdgcn_global_load_lds(Bl + rb, &sm[3][idx * 8], 16, 0, 0);
        }
        __syncthreads();
        #pragma unroll
        for (int kc = 0; kc < 2; ++kc) {
            short8 fa_h[2], fa_l[2], fb_h[2], fb_l[2];
            const int ch = kc * 2 + lhalf;
            #pragma unroll
            for (int mt = 0; mt < 2; ++mt) {
                const int rr = wr + mt * 32 + lrow;
                const int off = rr * 32 + ((ch ^ ((rr >> 1) & 3)) << 3);
                fa_h[mt] = *(const short8*)&sm[0][off];
                fa_l[mt] = *(const short8*)&sm[1][off];
            }
            #pragma unroll
            for (int nt = 0; nt < 2; ++nt) {
                const int rr = wc + nt * 32 + lrow;
                const int off = rr * 32 + ((ch ^ ((rr >> 1) & 3)) << 3);
                fb_h[nt] = *(const short8*)&sm[2][off];
                fb_l[nt] = *(const short8*)&sm[3][off];
            }
            #pragma unroll
            for (int mt = 0; mt < 2; ++mt)
                #pragma unroll
                for (int nt = 0; nt < 2; ++nt) {
                    acc[mt][nt] = __builtin_amdgcn_mfma_f32_32x32x16_bf16(fa_h[mt], fb_h[nt], acc[mt][nt], 0, 0, 0);
                    acc[mt][nt] = __builtin_amdgcn_mfma_f32_32x32x16_bf16(fa_h[mt], fb_l[nt], acc[mt][nt], 0, 0, 0);
                    acc[mt][nt] = __builtin_amdgcn_mfma_f32_32x32x16_bf16(fa_l[mt], fb_h[nt], acc[mt][nt], 0, 0, 0);
                }
        }
        __syncthreads();
    }

    #pragma unroll
    for (int mt = 0; mt < 2; ++mt) {
        #pragma unroll
        for (int nt = 0; nt < 2; ++nt) {
            const int col = bn + wc + nt * 32 + lrow;
            if (col < N) {
                const float bsv = (EPI == 3) ? 0.f : bias[col];
                #pragma unroll
                for (int i = 0; i < 16; ++i) {
                    const int row = bm + wr + mt * 32 + (i & 3) + 8 * (i >> 2) + 4 * lhalf;
                    float v = acc[mt][nt][i] + bsv;
                    const size_t o = (size_t)row * ldc + col;
                    if (EPI == 0) {
                        C[o] = v;
                    } else if (EPI == 1) {
                        C[o] = v + R[o];
                    } else if (EPI == 3) {
                        C[o] = C[o] + v;
                    } else {
                        const float gv = gelu_f(v);
                        const u16 h = f2bf(gv);
                        Ch[o] = h;
                        Cl[o] = f2bf(gv - bf2f(h));
                    }
                }
            }
        }
    }
}

// ---------------- MFMA flash attention, causal, head dim 64 ----------------
// 128 q-rows/block, 4 waves x 32-row strips, KV tile = 64.
// Swapped QK^T: S^T = mfma(A=K, B=Q) -> lane holds one q-row's keys (in-lane softmax).
// QK^T 3-term (KhQh + KlQh + KhQl); PV 2-term (Ph*Vh + Ph*Vl), P bf16 via per-wave LDS.
// Output written in place into qkv Q-slots as split bf16 (hi at [0,64), lo at [64,128) u16).
__global__ __launch_bounds__(256, 2) void attn_mfma(float* __restrict__ qkv)
{
    __shared__ __align__(16) u16 Qh[128 * 64], Ql[128 * 64];   // 32 KB
    __shared__ __align__(16) u16 Kh[64 * 64], Kl[64 * 64];     // 16 KB
    __shared__ __align__(16) u16 Vth[64 * 64], Vtl[64 * 64];   // 16 KB (c-major: row=c, col=key)
    __shared__ __align__(16) u16 Ps[4][32 * 64];               // 16 KB (per wave, row=qrow, col=key)

    const int tid = threadIdx.x;
    const int lane = tid & 63;
    const int wid = tid >> 6;
    const int l31 = lane & 31;
    const int lh  = lane >> 5;
    const int qi = (int)gridDim.x - 1 - (int)blockIdx.x;   // heavy blocks first
    const int q0 = qi * 128;
    const int bh = blockIdx.y;
    const int bb = bh / H_;
    const int h  = bh % H_;
    float* base = qkv + (size_t)bb * S_ * (3 * D_) + h * 64;

    // ---- stage Q (scaled by c^-0.5 = 0.125), split hi/lo ----
    #pragma unroll
    for (int p = 0; p < 8; ++p) {
        const int idx = p * 256 + tid;
        const int r = idx >> 4, c4 = (idx & 15) << 2;
        float4 v = *(const float4*)(base + (size_t)(q0 + r) * (3 * D_) + c4);
        v.x *= 0.125f; v.y *= 0.125f; v.z *= 0.125f; v.w *= 0.125f;
        ushort4 hv, lv;
        split2(v.x, hv.x, lv.x); split2(v.y, hv.y, lv.y);
        split2(v.z, hv.z, lv.z); split2(v.w, hv.w, lv.w);
        const int o = swz(r, c4);
        *(ushort4*)&Qh[o] = hv;
        *(ushort4*)&Ql[o] = lv;
    }
    __syncthreads();

    // ---- hoist this wave's Q fragments (B-operand: col=qrow, k=c) ----
    short8 fqh[4], fql[4];
    const int qrow = wid * 32 + l31;
    #pragma unroll
    for (int m = 0; m < 4; ++m) {
        const int o = swz(qrow, m * 16 + lh * 8);
        fqh[m] = *(const short8*)&Qh[o];
        fql[m] = *(const short8*)&Ql[o];
    }

    f32x16 o0, o1;
    #pragma unroll
    for (int i = 0; i < 16; ++i) { o0[i] = 0.f; o1[i] = 0.f; }
    float m_run = -INFINITY, l_run = 0.f;
    const int wq0 = q0 + wid * 32;
    const int myq = wq0 + l31;
    const int ntiles = q0 / 64 + 2;

    for (int t = 0; t < ntiles; ++t) {
        const int k0 = t * 64;
        __syncthreads();   // previous tile's K/V reads complete
        // ---- stage K (row-major, split) and V (transposed c-major, split) ----
        #pragma unroll
        for (int p = 0; p < 4; ++p) {
            const int idx = p * 256 + tid;
            const int r = idx >> 4, c4 = (idx & 15) << 2;
            const float* krow = base + D_ + (size_t)(k0 + r) * (3 * D_);
            const float4 kv = *(const float4*)(krow + c4);
            ushort4 hv, lv;
            split2(kv.x, hv.x, lv.x); split2(kv.y, hv.y, lv.y);
            split2(kv.z, hv.z, lv.z); split2(kv.w, hv.w, lv.w);
            const int o = swz(r, c4);
            *(ushort4*)&Kh[o] = hv;
            *(ushort4*)&Kl[o] = lv;
            const float4 vv = *(const float4*)(krow + D_ + c4);
            u16 vh, vl;
            split2(vv.x, vh, vl); Vth[swz(c4 + 0, r)] = vh; Vtl[swz(c4 + 0, r)] = vl;
            split2(vv.y, vh, vl); Vth[swz(c4 + 1, r)] = vh; Vtl[swz(c4 + 1, r)] = vl;
            split2(vv.z, vh, vl); Vth[swz(c4 + 2, r)] = vh; Vtl[swz(c4 + 2, r)] = vl;
            split2(vv.w, vh, vl); Vth[swz(c4 + 3, r)] = vh; Vtl[swz(c4 + 3, r)] = vl;
        }
        __syncthreads();

        if (k0 < wq0 + 32) {   // causal participation for this wave
            // ---- S^T = K . Q^T (3-term split), two 32-key subtiles ----
            f32x16 s0, s1;
            #pragma unroll
            for (int i = 0; i < 16; ++i) { s0[i] = 0.f; s1[i] = 0.f; }
            #pragma unroll
            for (int m = 0; m < 4; ++m) {
                const int co = m * 16 + lh * 8;
                const int oa0 = swz(l31, co);
                const int oa1 = swz(32 + l31, co);
                short8 kh0 = *(const short8*)&Kh[oa0];
                short8 kl0 = *(const short8*)&Kl[oa0];
                short8 kh1 = *(const short8*)&Kh[oa1];
                short8 kl1 = *(const short8*)&Kl[oa1];
                s0 = __builtin_amdgcn_mfma_f32_32x32x16_bf16(kh0, fqh[m], s0, 0, 0, 0);
                s0 = __builtin_amdgcn_mfma_f32_32x32x16_bf16(kl0, fqh[m], s0, 0, 0, 0);
                s0 = __builtin_amdgcn_mfma_f32_32x32x16_bf16(kh0, fql[m], s0, 0, 0, 0);
                s1 = __builtin_amdgcn_mfma_f32_32x32x16_bf16(kh1, fqh[m], s1, 0, 0, 0);
                s1 = __builtin_amdgcn_mfma_f32_32x32x16_bf16(kl1, fqh[m], s1, 0, 0, 0);
                s1 = __builtin_amdgcn_mfma_f32_32x32x16_bf16(kh1, fql[m], s1, 0, 0, 0);
            }

            // ---- causal mask + online softmax (per-lane row = myq) ----
            float smax = -INFINITY;
            #pragma unroll
            for (int i = 0; i < 16; ++i) {
                const int kb = (i & 3) + 8 * (i >> 2) + 4 * lh;
                float x0 = (k0 + kb > myq) ? -INFINITY : s0[i];
                float x1 = (k0 + 32 + kb > myq) ? -INFINITY : s1[i];
                s0[i] = x0; s1[i] = x1;
                smax = fmaxf(smax, fmaxf(x0, x1));
            }
            smax = fmaxf(smax, __shfl_xor(smax, 32));
            const float mn = fmaxf(m_run, smax);
            const float sc = __expf(m_run - mn);
            m_run = mn;
            float ls = 0.f;
            #pragma unroll
            for (int i = 0; i < 16; ++i) {
                const float p0 = __expf(s0[i] - mn);
                const float p1 = __expf(s1[i] - mn);
                s0[i] = p0; s1[i] = p1;
                ls += p0 + p1;
            }
            ls += __shfl_xor(ls, 32);
            l_run = l_run * sc + ls;

            // ---- pack P pairs -> per-wave LDS (row=qrow l31, col=key) ----
            #pragma unroll
            for (int j = 0; j < 8; ++j) {
                const int i = 2 * j;
                const int kb = (i & 3) + 8 * (i >> 2) + 4 * lh;
                unsigned pk0 = (unsigned)f2bf(s0[i]) | ((unsigned)f2bf(s0[i + 1]) << 16);
                unsigned pk1 = (unsigned)f2bf(s1[i]) | ((unsigned)f2bf(s1[i + 1]) << 16);
                *(unsigned*)&Ps[wid][swz(l31, kb)]      = pk0;
                *(unsigned*)&Ps[wid][swz(l31, 32 + kb)] = pk1;
            }

            // ---- rescale O by per-row exp(m_old - m_new) ----
            float scs[16];
            #pragma unroll
            for (int i = 0; i < 16; ++i)
                scs[i] = __shfl(sc, (i & 3) + 8 * (i >> 2) + 4 * lh);
            #pragma unroll
            for (int i = 0; i < 16; ++i) { o0[i] *= scs[i]; o1[i] *= scs[i]; }

            // ---- O += P . V (A=P from own-wave LDS, B=V^T, 2-term V) ----
            #pragma unroll
            for (int m = 0; m < 4; ++m) {
                const int co = m * 16 + lh * 8;
                short8 fp   = *(const short8*)&Ps[wid][swz(l31, co)];
                short8 fv0h = *(const short8*)&Vth[swz(l31, co)];
                short8 fv0l = *(const short8*)&Vtl[swz(l31, co)];
                short8 fv1h = *(const short8*)&Vth[swz(32 + l31, co)];
                short8 fv1l = *(const short8*)&Vtl[swz(32 + l31, co)];
                o0 = __builtin_amdgcn_mfma_f32_32x32x16_bf16(fp, fv0h, o0, 0, 0, 0);
                o0 = __builtin_amdgcn_mfma_f32_32x32x16_bf16(fp, fv0l, o0, 0, 0, 0);
                o1 = __builtin_amdgcn_mfma_f32_32x32x16_bf16(fp, fv1h, o1, 0, 0, 0);
                o1 = __builtin_amdgcn_mfma_f32_32x32x16_bf16(fp, fv1l, o1, 0, 0, 0);
            }
        }
    }

    // ---- normalize + write split bf16 into Q-slots (in place) ----
    const float inv = 1.f / l_run;
    #pragma unroll
    for (int i = 0; i < 16; ++i) {
        const int ri = (i & 3) + 8 * (i >> 2) + 4 * lh;
        const float sci = __shfl(inv, ri);
        const int r = q0 + wid * 32 + ri;
        u16* ph = (u16*)(base + (size_t)r * (3 * D_));
        const float a0 = o0[i] * sci;
        const float a1 = o1[i] * sci;
        const u16 h0 = f2bf(a0), h1 = f2bf(a1);
        ph[l31]      = h0;
        ph[64 + l31] = f2bf(a0 - bf2f(h0));
        ph[32 + l31]      = h1;
        ph[64 + 32 + l31] = f2bf(a1 - bf2f(h1));
    }
}

extern "C" void kernel_launch(void* const* d_in, const int* in_sizes, int n_in,
                              void* d_out, int out_size, void* d_ws, size_t ws_size,
                              hipStream_t stream) {
    const float* x         = (const float*)d_in[0];
    const float* g1        = (const float*)d_in[1];
    const float* b1        = (const float*)d_in[2];
    const float* w_qkv     = (const float*)d_in[3];
    const float* bias_qkv  = (const float*)d_in[4];
    const float* w_proj    = (const float*)d_in[5];
    const float* bias_proj = (const float*)d_in[6];
    const float* g2        = (const float*)d_in[7];
    const float* b2        = (const float*)d_in[8];
    const float* w_fc      = (const float*)d_in[9];
    const float* bias_fc   = (const float*)d_in[10];
    const float* w_out     = (const float*)d_in[11];
    const float* bias_out  = (const float*)d_in[12];
    float* out = (float*)d_out;
    char* W = (char*)d_ws;

    // workspace layout (bytes), peak 152,371,200 (< 157,286,400 proven safe):
    u16*   xnh  = (u16*)  (W + 0);           // 13,107,200
    u16*   xnl  = (u16*)  (W + 13107200);    // 13,107,200
    float* x1   = (float*)(W + 26214400);    // 26,214,400
    float* qkv  = (float*)(W + 52428800);    // 78,643,200 (f32 [2][2048][4800])
    u16*   hdnh = (u16*)  (W + 52428800);    // 26,214,400 (reuse qkv region)
    u16*   hdnl = (u16*)  (W + 78643200);    // 26,214,400
    u16*   wh   = (u16*)  (W + 131072000);   // 10,649,600
    u16*   wl   = (u16*)  (W + 141721600);   // 10,649,600 -> ends 152,371,200

    dim3 blk(256);

    // 1. LN1 -> split
    ln_split_kernel<<<4096, blk, 0, stream>>>(x, g1, b1, xnh, xnl);

    // 2. qkv = xn @ w_qkv + bias, two column-halves (N=2400, padded to 2432)
    for (int ci = 0; ci < 2; ++ci) {
        wsplit_kernel<<<dim3(76, 50), blk, 0, stream>>>(w_qkv + ci * 2400, 4800, wh, wl, 1600, 2400);
        mgemm<0, 0><<<dim3(19, 32), blk, 0, stream>>>(
            (const char*)xnh, (const char*)xnl, 3200L, wh, wl,
            bias_qkv + ci * 2400, nullptr, qkv + ci * 2400, nullptr, nullptr,
            4800, 2400, 1600);
    }

    // 3. MFMA flash attention (in-place split-bf16 output into Q-slots)
    attn_mfma<<<dim3(16, 50), blk, 0, stream>>>(qkv);

    // 4. x1 = att @ w_proj + bias + x   (A from Q-slots, AMODE=1)
    wsplit_kernel<<<dim3(52, 50), blk, 0, stream>>>(w_proj, 1600, wh, wl, 1600, 1600);
    mgemm<1, 1><<<dim3(13, 32), blk, 0, stream>>>(
        (const char*)qkv, (const char*)qkv + 128, 19200L, wh, wl,
        bias_proj, x, x1, nullptr, nullptr, 1600, 1600, 1600);

    // 5. LN2 -> split
    ln_split_kernel<<<4096, blk, 0, stream>>>(x1, g2, b2, xnh, xnl);

    // 6+7. MLP in two K-chunks of 3200
    for (int ci = 0; ci < 2; ++ci) {
        wsplit_kernel<<<dim3(100, 50), blk, 0, stream>>>(w_fc + ci * 3200, 6400, wh, wl, 1600, 3200);
        mgemm<2, 0><<<dim3(25, 32), blk, 0, stream>>>(
            (const char*)xnh, (const char*)xnl, 3200L, wh, wl,
            bias_fc + ci * 3200, nullptr, nullptr, hdnh, hdnl,
            3200, 3200, 1600);
        wsplit_kernel<<<dim3(52, 100), blk, 0, stream>>>(w_out + (size_t)ci * 3200 * 1600, 1600, wh, wl, 3200, 1600);
        if (ci == 0) {
            mgemm<1, 0><<<dim3(13, 32), blk, 0, stream>>>(
                (const char*)hdnh, (const char*)hdnl, 6400L, wh, wl,
                bias_out, x1, out, nullptr, nullptr, 1600, 1600, 3200);
        } else {
            mgemm<3, 0><<<dim3(13, 32), blk, 0, stream>>>(
                (const char*)hdnh, (const char*)hdnl, 6400L, wh, wl,
                bias_out, nullptr, out, nullptr, nullptr, 1600, 1600, 3200);
        }
    }
}

// Round 6
// 827.301 us; speedup vs baseline: 5.4615x; 1.7418x over previous
//
#include <hip/hip_runtime.h>
#include <math.h>

#define S_ 2048
#define D_ 1600
#define H_ 25

typedef unsigned short u16;
typedef __attribute__((ext_vector_type(8))) short short8;
typedef __attribute__((ext_vector_type(16))) float f32x16;

static __device__ __forceinline__ u16 f2h(float f) {
    union { _Float16 h; u16 u; } c;
    c.h = (_Float16)f;            // v_cvt_f16_f32, RTN
    return c.u;
}

__device__ __forceinline__ float gelu_f(float x) {
    float x3 = x * x * x;
    return 0.5f * x * (1.0f + tanhf(0.7978845608028654f * (x + 0.044715f * x3)));
}

// chunk-XOR swizzle for f16 tiles with 64-elem (128 B) rows: 16B chunk ^= row&7
__device__ __forceinline__ int swz(int row, int col) {
    return row * 64 + ((((col >> 3) ^ row) & 7) << 3) + (col & 7);
}

// ---------------- weight convert+transpose: W[K][ldW] fp32 -> WT [Np][K] fp16 ----------------
// grid (Np/32, K/32); pad rows (n0 >= N) zero-filled every call (ws is re-poisoned).
__global__ __launch_bounds__(256) void wconv_kernel(
    const float* __restrict__ W, int ldW, u16* __restrict__ T, int K, int N)
{
    __shared__ __align__(16) float tile[32][33];
    const int tid = threadIdx.x;
    const int n0 = blockIdx.x * 32;
    const int k0 = blockIdx.y * 32;
    const int r = tid >> 3, cq = tid & 7;
    if (n0 < N) {
        const float4 v = *(const float4*)(W + (size_t)(k0 + r) * ldW + n0 + cq * 4);
        tile[r][cq * 4 + 0] = v.x; tile[r][cq * 4 + 1] = v.y;
        tile[r][cq * 4 + 2] = v.z; tile[r][cq * 4 + 3] = v.w;
    }
    __syncthreads();
    const int n = tid >> 3, kq = tid & 7;
    ushort4 hv = make_ushort4(0, 0, 0, 0);
    if (n0 < N) {
        hv = make_ushort4(f2h(tile[kq * 4 + 0][n]), f2h(tile[kq * 4 + 1][n]),
                          f2h(tile[kq * 4 + 2][n]), f2h(tile[kq * 4 + 3][n]));
    }
    *(ushort4*)(T + (size_t)(n0 + n) * K + k0 + kq * 4) = hv;
}

// ---------------- LayerNorm -> fp16 output ----------------
__global__ __launch_bounds__(256) void ln_f16_kernel(
    const float* __restrict__ x, const float* __restrict__ g,
    const float* __restrict__ bb, u16* __restrict__ y)
{
    const int row = blockIdx.x;
    const float* xr = x + (size_t)row * D_;
    const int tid = threadIdx.x;

    float4 a0 = ((const float4*)xr)[tid];
    float4 a1 = make_float4(0.f, 0.f, 0.f, 0.f);
    const bool has2 = tid < (D_ / 4 - 256);
    if (has2) a1 = ((const float4*)xr)[256 + tid];

    float s  = a0.x + a0.y + a0.z + a0.w + a1.x + a1.y + a1.z + a1.w;
    float s2 = a0.x*a0.x + a0.y*a0.y + a0.z*a0.z + a0.w*a0.w
             + a1.x*a1.x + a1.y*a1.y + a1.z*a1.z + a1.w*a1.w;

    #pragma unroll
    for (int m = 32; m >= 1; m >>= 1) {
        s  += __shfl_xor(s,  m);
        s2 += __shfl_xor(s2, m);
    }
    __shared__ float red[8];
    const int lane = tid & 63, wv = tid >> 6;
    if (lane == 0) { red[wv] = s; red[4 + wv] = s2; }
    __syncthreads();
    if (tid == 0) {
        red[0] = red[0] + red[1] + red[2] + red[3];
        red[4] = red[4] + red[5] + red[6] + red[7];
    }
    __syncthreads();
    const float mean = red[0] * (1.f / D_);
    const float var  = red[4] * (1.f / D_) - mean * mean;
    const float rstd = rsqrtf(var + 1e-5f);

    u16* yr = y + (size_t)row * D_;
    float4 gv = ((const float4*)g)[tid];
    float4 bv = ((const float4*)bb)[tid];
    ((ushort4*)yr)[tid] = make_ushort4(
        f2h((a0.x - mean) * rstd * gv.x + bv.x),
        f2h((a0.y - mean) * rstd * gv.y + bv.y),
        f2h((a0.z - mean) * rstd * gv.z + bv.z),
        f2h((a0.w - mean) * rstd * gv.w + bv.w));
    if (has2) {
        gv = ((const float4*)g)[256 + tid];
        bv = ((const float4*)bb)[256 + tid];
        ((ushort4*)yr)[256 + tid] = make_ushort4(
            f2h((a1.x - mean) * rstd * gv.x + bv.x),
            f2h((a1.y - mean) * rstd * gv.y + bv.y),
            f2h((a1.z - mean) * rstd * gv.z + bv.z),
            f2h((a1.w - mean) * rstd * gv.w + bv.w));
    }
}

// ---------------- fp16 MFMA GEMM: C = A @ B^T (+bias, epilogues) ----------------
// A: AMODE 0 = dense fp16 [M][K] (row stride lda BYTES); AMODE 1 = qkv Q-slot fp16
//    (row stride lda bytes, k -> (k/64)*256 + (k%64)*2 byte offset).
// B: fp16 [Np][K]. EPI: 0 = C+bias; 1 = C+bias+R; 2 = gelu -> fp16 Ch.
template<int EPI, int AMODE>
__global__ __launch_bounds__(256, 4) void mgemm(
    const char* __restrict__ Ab, long lda, const u16* __restrict__ B,
    const float* __restrict__ bias, const float* __restrict__ R,
    float* __restrict__ C, u16* __restrict__ Ch,
    int ldc, int N, int K)
{
    __shared__ __align__(16) u16 sm[2][4096];   // A,B tiles: 128 rows x 32 k, chunk-swizzled
    const int tid = threadIdx.x;

    // XCD-bijective swizzle (all grids have nwg % 8 == 0)
    const int gx = gridDim.x;
    const int nwg = gx * (int)gridDim.y;
    const int bid0 = blockIdx.y * gx + blockIdx.x;
    const int cpx = nwg >> 3;
    const int bid = (bid0 & 7) * cpx + (bid0 >> 3);
    const int bn = (bid % gx) * 128;
    const int bm = (bid / gx) * 128;

    const int lrow  = tid & 31;
    const int lhalf = (tid >> 5) & 1;
    const int wid   = tid >> 6;
    const int wr = (wid >> 1) * 64;
    const int wc = (wid & 1) * 64;

    f32x16 acc[2][2];
    #pragma unroll
    for (int mt = 0; mt < 2; ++mt)
        #pragma unroll
        for (int nt = 0; nt < 2; ++nt)
            #pragma unroll
            for (int i = 0; i < 16; ++i) acc[mt][nt][i] = 0.f;

    for (int k0 = 0; k0 < K; k0 += 32) {
        #pragma unroll
        for (int p = 0; p < 2; ++p) {
            const int idx = p * 256 + tid;
            const int r = idx >> 2, pch = idx & 3;
            const int c = pch ^ ((r >> 1) & 3);
            const int ke = k0 + c * 8;
            const size_t ka = (AMODE == 0) ? (size_t)ke * 2
                                           : (size_t)(((ke >> 6) << 8) + ((ke & 63) << 1));
            __builtin_amdgcn_global_load_lds((const u16*)(Ab + (size_t)(bm + r) * lda + ka),
                                             &sm[0][idx * 8], 16, 0, 0);
            __builtin_amdgcn_global_load_lds(B + (size_t)(bn + r) * K + ke,
                                             &sm[1][idx * 8], 16, 0, 0);
        }
        __syncthreads();
        #pragma unroll
        for (int kc = 0; kc < 2; ++kc) {
            short8 fa[2], fb[2];
            const int ch = kc * 2 + lhalf;
            #pragma unroll
            for (int mt = 0; mt < 2; ++mt) {
                const int rr = wr + mt * 32 + lrow;
                fa[mt] = *(const short8*)&sm[0][rr * 32 + ((ch ^ ((rr >> 1) & 3)) << 3)];
            }
            #pragma unroll
            for (int nt = 0; nt < 2; ++nt) {
                const int rr = wc + nt * 32 + lrow;
                fb[nt] = *(const short8*)&sm[1][rr * 32 + ((ch ^ ((rr >> 1) & 3)) << 3)];
            }
            #pragma unroll
            for (int mt = 0; mt < 2; ++mt)
                #pragma unroll
                for (int nt = 0; nt < 2; ++nt)
                    acc[mt][nt] = __builtin_amdgcn_mfma_f32_32x32x16_f16(fa[mt], fb[nt], acc[mt][nt], 0, 0, 0);
        }
        __syncthreads();
    }

    // epilogue: C/D layout col = lane&31, row = (i&3) + 8*(i>>2) + 4*(lane>>5)
    #pragma unroll
    for (int mt = 0; mt < 2; ++mt) {
        #pragma unroll
        for (int nt = 0; nt < 2; ++nt) {
            const int col = bn + wc + nt * 32 + lrow;
            if (col < N) {
                const float bsv = bias[col];
                #pragma unroll
                for (int i = 0; i < 16; ++i) {
                    const int row = bm + wr + mt * 32 + (i & 3) + 8 * (i >> 2) + 4 * lhalf;
                    float v = acc[mt][nt][i] + bsv;
                    const size_t o = (size_t)row * ldc + col;
                    if (EPI == 0) {
                        C[o] = v;
                    } else if (EPI == 1) {
                        C[o] = v + R[o];
                    } else {
                        Ch[o] = f2h(gelu_f(v));
                    }
                }
            }
        }
    }
}

// ---------------- fp16 MFMA flash attention, causal, head dim 64 ----------------
// 128 q-rows/block, 4 waves x 32-row strips, KV tile 64. Swapped QK^T (lane = q-row).
// Output written in place into qkv Q-slots as fp16 (u16[0..64) of each slot).
__global__ __launch_bounds__(256, 3) void attn_mfma(float* __restrict__ qkv)
{
    __shared__ __align__(16) u16 Qs[128 * 64];    // 16 KB
    __shared__ __align__(16) u16 Ks[64 * 64];     // 8 KB
    __shared__ __align__(16) u16 Vt[64 * 64];     // 8 KB (c-major: row=c, col=key)
    __shared__ __align__(16) u16 Ps[4][32 * 64];  // 16 KB (per wave, row=qrow, col=key)

    const int tid = threadIdx.x;
    const int lane = tid & 63;
    const int wid = tid >> 6;
    const int l31 = lane & 31;
    const int lh  = lane >> 5;
    const int qi = (int)gridDim.x - 1 - (int)blockIdx.x;   // heavy blocks first
    const int q0 = qi * 128;
    const int bh = blockIdx.y;
    const int bb = bh / H_;
    const int h  = bh % H_;
    float* base = qkv + (size_t)bb * S_ * (3 * D_) + h * 64;

    // ---- stage Q (scaled by 0.125) as fp16 ----
    #pragma unroll
    for (int p = 0; p < 8; ++p) {
        const int idx = p * 256 + tid;
        const int r = idx >> 4, c4 = (idx & 15) << 2;
        const float4 v = *(const float4*)(base + (size_t)(q0 + r) * (3 * D_) + c4);
        *(ushort4*)&Qs[swz(r, c4)] = make_ushort4(
            f2h(v.x * 0.125f), f2h(v.y * 0.125f), f2h(v.z * 0.125f), f2h(v.w * 0.125f));
    }
    __syncthreads();

    // ---- hoist this wave's Q fragments (B-operand: col=qrow, k=c) ----
    short8 fq[4];
    const int qrow = wid * 32 + l31;
    #pragma unroll
    for (int m = 0; m < 4; ++m)
        fq[m] = *(const short8*)&Qs[swz(qrow, m * 16 + lh * 8)];

    f32x16 o0, o1;
    #pragma unroll
    for (int i = 0; i < 16; ++i) { o0[i] = 0.f; o1[i] = 0.f; }
    float m_run = -INFINITY, l_run = 0.f;
    const int wq0 = q0 + wid * 32;
    const int myq = wq0 + l31;
    const int ntiles = q0 / 64 + 2;

    for (int t = 0; t < ntiles; ++t) {
        const int k0 = t * 64;
        __syncthreads();   // previous tile's K/V reads complete
        // ---- stage K (row-major) and V (transposed c-major) as fp16 ----
        #pragma unroll
        for (int p = 0; p < 4; ++p) {
            const int idx = p * 256 + tid;
            const int r = idx >> 4, c4 = (idx & 15) << 2;
            const float* krow = base + D_ + (size_t)(k0 + r) * (3 * D_);
            const float4 kv = *(const float4*)(krow + c4);
            *(ushort4*)&Ks[swz(r, c4)] = make_ushort4(f2h(kv.x), f2h(kv.y), f2h(kv.z), f2h(kv.w));
            const float4 vv = *(const float4*)(krow + D_ + c4);
            Vt[swz(c4 + 0, r)] = f2h(vv.x);
            Vt[swz(c4 + 1, r)] = f2h(vv.y);
            Vt[swz(c4 + 2, r)] = f2h(vv.z);
            Vt[swz(c4 + 3, r)] = f2h(vv.w);
        }
        __syncthreads();

        if (k0 < wq0 + 32) {   // causal participation for this wave
            // ---- S^T = K . Q^T, two 32-key subtiles ----
            f32x16 s0, s1;
            #pragma unroll
            for (int i = 0; i < 16; ++i) { s0[i] = 0.f; s1[i] = 0.f; }
            #pragma unroll
            for (int m = 0; m < 4; ++m) {
                const int co = m * 16 + lh * 8;
                short8 k0f = *(const short8*)&Ks[swz(l31, co)];
                short8 k1f = *(const short8*)&Ks[swz(32 + l31, co)];
                s0 = __builtin_amdgcn_mfma_f32_32x32x16_f16(k0f, fq[m], s0, 0, 0, 0);
                s1 = __builtin_amdgcn_mfma_f32_32x32x16_f16(k1f, fq[m], s1, 0, 0, 0);
            }

            // ---- causal mask + online softmax (per-lane row = myq) ----
            float smax = -INFINITY;
            #pragma unroll
            for (int i = 0; i < 16; ++i) {
                const int kb = (i & 3) + 8 * (i >> 2) + 4 * lh;
                float x0 = (k0 + kb > myq) ? -INFINITY : s0[i];
                float x1 = (k0 + 32 + kb > myq) ? -INFINITY : s1[i];
                s0[i] = x0; s1[i] = x1;
                smax = fmaxf(smax, fmaxf(x0, x1));
            }
            smax = fmaxf(smax, __shfl_xor(smax, 32));
            const float mn = fmaxf(m_run, smax);
            const float sc = __expf(m_run - mn);
            m_run = mn;
            float ls = 0.f;
            #pragma unroll
            for (int i = 0; i < 16; ++i) {
                const float p0 = __expf(s0[i] - mn);
                const float p1 = __expf(s1[i] - mn);
                s0[i] = p0; s1[i] = p1;
                ls += p0 + p1;
            }
            ls += __shfl_xor(ls, 32);
            l_run = l_run * sc + ls;

            // ---- pack P -> fp16 pairs in per-wave LDS (row=qrow, col=key) ----
            #pragma unroll
            for (int j = 0; j < 8; ++j) {
                const int i = 2 * j;
                const int kb = (i & 3) + 8 * (i >> 2) + 4 * lh;
                unsigned pk0 = (unsigned)f2h(s0[i]) | ((unsigned)f2h(s0[i + 1]) << 16);
                unsigned pk1 = (unsigned)f2h(s1[i]) | ((unsigned)f2h(s1[i + 1]) << 16);
                *(unsigned*)&Ps[wid][swz(l31, kb)]      = pk0;
                *(unsigned*)&Ps[wid][swz(l31, 32 + kb)] = pk1;
            }

            // ---- rescale O ----
            float scs[16];
            #pragma unroll
            for (int i = 0; i < 16; ++i)
                scs[i] = __shfl(sc, (i & 3) + 8 * (i >> 2) + 4 * lh);
            #pragma unroll
            for (int i = 0; i < 16; ++i) { o0[i] *= scs[i]; o1[i] *= scs[i]; }

            // ---- O += P . V ----
            #pragma unroll
            for (int m = 0; m < 4; ++m) {
                const int co = m * 16 + lh * 8;
                short8 fp  = *(const short8*)&Ps[wid][swz(l31, co)];
                short8 fv0 = *(const short8*)&Vt[swz(l31, co)];
                short8 fv1 = *(const short8*)&Vt[swz(32 + l31, co)];
                o0 = __builtin_amdgcn_mfma_f32_32x32x16_f16(fp, fv0, o0, 0, 0, 0);
                o1 = __builtin_amdgcn_mfma_f32_32x32x16_f16(fp, fv1, o1, 0, 0, 0);
            }
        }
    }

    // ---- normalize + write fp16 into Q-slots (in place) ----
    const float inv = 1.f / l_run;
    #pragma unroll
    for (int i = 0; i < 16; ++i) {
        const int ri = (i & 3) + 8 * (i >> 2) + 4 * lh;
        const float sci = __shfl(inv, ri);
        u16* ph = (u16*)(base + (size_t)(q0 + wid * 32 + ri) * (3 * D_));
        ph[l31]      = f2h(o0[i] * sci);
        ph[32 + l31] = f2h(o1[i] * sci);
    }
}

extern "C" void kernel_launch(void* const* d_in, const int* in_sizes, int n_in,
                              void* d_out, int out_size, void* d_ws, size_t ws_size,
                              hipStream_t stream) {
    const float* x         = (const float*)d_in[0];
    const float* g1        = (const float*)d_in[1];
    const float* b1        = (const float*)d_in[2];
    const float* w_qkv     = (const float*)d_in[3];
    const float* bias_qkv  = (const float*)d_in[4];
    const float* w_proj    = (const float*)d_in[5];
    const float* bias_proj = (const float*)d_in[6];
    const float* g2        = (const float*)d_in[7];
    const float* b2        = (const float*)d_in[8];
    const float* w_fc      = (const float*)d_in[9];
    const float* bias_fc   = (const float*)d_in[10];
    const float* w_out     = (const float*)d_in[11];
    const float* bias_out  = (const float*)d_in[12];
    float* out = (float*)d_out;
    char* W = (char*)d_ws;

    // workspace layout (bytes), peak 140,902,400 (< 152,371,200 proven safe):
    u16*   xn  = (u16*)  (W + 0);            // 13,107,200  fp16 [4096][1600]
    float* x1  = (float*)(W + 13107200);     // 26,214,400
    float* qkv = (float*)(W + 39321600);     // 78,643,200  f32 [2][2048][4800]
    u16*   hdn = (u16*)  (W + 39321600);     // 52,428,800  fp16 [4096][6400] (reuses qkv)
    u16*   wT  = (u16*)  (W + 117964800);    // up to 22,937,600 -> ends 140,902,400

    dim3 blk(256);

    // 1. LN1 -> fp16
    ln_f16_kernel<<<4096, blk, 0, stream>>>(x, g1, b1, xn);

    // 2. qkv = xn @ w_qkv + bias (fp32 out), Np=4864
    wconv_kernel<<<dim3(152, 50), blk, 0, stream>>>(w_qkv, 4800, wT, 1600, 4800);
    mgemm<0, 0><<<dim3(38, 32), blk, 0, stream>>>(
        (const char*)xn, 3200L, wT, bias_qkv, nullptr, qkv, nullptr, 4800, 4800, 1600);

    // 3. MFMA flash attention (in-place fp16 output into Q-slots)
    attn_mfma<<<dim3(16, 50), blk, 0, stream>>>(qkv);

    // 4. x1 = att @ w_proj + bias + x   (A from Q-slots, AMODE=1), Np=1792
    wconv_kernel<<<dim3(56, 50), blk, 0, stream>>>(w_proj, 1600, wT, 1600, 1600);
    mgemm<1, 1><<<dim3(13, 32), blk, 0, stream>>>(
        (const char*)qkv, 19200L, wT, bias_proj, x, x1, nullptr, 1600, 1600, 1600);

    // 5. LN2 -> fp16
    ln_f16_kernel<<<4096, blk, 0, stream>>>(x1, g2, b2, xn);

    // 6. hdn = gelu(xn @ w_fc + bias) -> fp16, Np=6400
    wconv_kernel<<<dim3(200, 50), blk, 0, stream>>>(w_fc, 6400, wT, 1600, 6400);
    mgemm<2, 0><<<dim3(50, 32), blk, 0, stream>>>(
        (const char*)xn, 3200L, wT, bias_fc, nullptr, nullptr, hdn, 6400, 6400, 1600);

    // 7. out = hdn @ w_out + bias + x1  (K=6400 single pass), Np=1792
    wconv_kernel<<<dim3(56, 200), blk, 0, stream>>>(w_out, 1600, wT, 6400, 1600);
    mgemm<1, 0><<<dim3(13, 32), blk, 0, stream>>>(
        (const char*)hdn, 12800L, wT, bias_out, x1, out, nullptr, 1600, 1600, 6400);
}

// Round 7
// 708.616 us; speedup vs baseline: 6.3763x; 1.1675x over previous
//
#include <hip/hip_runtime.h>
#include <math.h>

#define S_ 2048
#define D_ 1600
#define H_ 25

typedef unsigned short u16;
typedef __attribute__((ext_vector_type(8))) short short8;
typedef __attribute__((ext_vector_type(16))) float f32x16;

static __device__ __forceinline__ u16 f2h(float f) {
    union { _Float16 h; u16 u; } c;
    c.h = (_Float16)f;            // v_cvt_f16_f32, RTN
    return c.u;
}

__device__ __forceinline__ float gelu_f(float x) {
    float x3 = x * x * x;
    return 0.5f * x * (1.0f + tanhf(0.7978845608028654f * (x + 0.044715f * x3)));
}

// chunk-XOR swizzle for f16 tiles with 64-elem (128 B) rows: 16B chunk ^= row&7
__device__ __forceinline__ int swz(int row, int col) {
    return row * 64 + ((((col >> 3) ^ row) & 7) << 3) + (col & 7);
}

// ---------------- weight convert+transpose: W[K][ldW] fp32 -> WT [Np][K] fp16 ----------------
__global__ __launch_bounds__(256) void wconv_kernel(
    const float* __restrict__ W, int ldW, u16* __restrict__ T, int K, int N)
{
    __shared__ __align__(16) float tile[32][33];
    const int tid = threadIdx.x;
    const int n0 = blockIdx.x * 32;
    const int k0 = blockIdx.y * 32;
    const int r = tid >> 3, cq = tid & 7;
    if (n0 < N) {
        const float4 v = *(const float4*)(W + (size_t)(k0 + r) * ldW + n0 + cq * 4);
        tile[r][cq * 4 + 0] = v.x; tile[r][cq * 4 + 1] = v.y;
        tile[r][cq * 4 + 2] = v.z; tile[r][cq * 4 + 3] = v.w;
    }
    __syncthreads();
    const int n = tid >> 3, kq = tid & 7;
    ushort4 hv = make_ushort4(0, 0, 0, 0);
    if (n0 < N) {
        hv = make_ushort4(f2h(tile[kq * 4 + 0][n]), f2h(tile[kq * 4 + 1][n]),
                          f2h(tile[kq * 4 + 2][n]), f2h(tile[kq * 4 + 3][n]));
    }
    *(ushort4*)(T + (size_t)(n0 + n) * K + k0 + kq * 4) = hv;
}

// ---------------- LayerNorm -> fp16 output ----------------
__global__ __launch_bounds__(256) void ln_f16_kernel(
    const float* __restrict__ x, const float* __restrict__ g,
    const float* __restrict__ bb, u16* __restrict__ y)
{
    const int row = blockIdx.x;
    const float* xr = x + (size_t)row * D_;
    const int tid = threadIdx.x;

    float4 a0 = ((const float4*)xr)[tid];
    float4 a1 = make_float4(0.f, 0.f, 0.f, 0.f);
    const bool has2 = tid < (D_ / 4 - 256);
    if (has2) a1 = ((const float4*)xr)[256 + tid];

    float s  = a0.x + a0.y + a0.z + a0.w + a1.x + a1.y + a1.z + a1.w;
    float s2 = a0.x*a0.x + a0.y*a0.y + a0.z*a0.z + a0.w*a0.w
             + a1.x*a1.x + a1.y*a1.y + a1.z*a1.z + a1.w*a1.w;

    #pragma unroll
    for (int m = 32; m >= 1; m >>= 1) {
        s  += __shfl_xor(s,  m);
        s2 += __shfl_xor(s2, m);
    }
    __shared__ float red[8];
    const int lane = tid & 63, wv = tid >> 6;
    if (lane == 0) { red[wv] = s; red[4 + wv] = s2; }
    __syncthreads();
    if (tid == 0) {
        red[0] = red[0] + red[1] + red[2] + red[3];
        red[4] = red[4] + red[5] + red[6] + red[7];
    }
    __syncthreads();
    const float mean = red[0] * (1.f / D_);
    const float var  = red[4] * (1.f / D_) - mean * mean;
    const float rstd = rsqrtf(var + 1e-5f);

    u16* yr = y + (size_t)row * D_;
    float4 gv = ((const float4*)g)[tid];
    float4 bv = ((const float4*)bb)[tid];
    ((ushort4*)yr)[tid] = make_ushort4(
        f2h((a0.x - mean) * rstd * gv.x + bv.x),
        f2h((a0.y - mean) * rstd * gv.y + bv.y),
        f2h((a0.z - mean) * rstd * gv.z + bv.z),
        f2h((a0.w - mean) * rstd * gv.w + bv.w));
    if (has2) {
        gv = ((const float4*)g)[256 + tid];
        bv = ((const float4*)bb)[256 + tid];
        ((ushort4*)yr)[256 + tid] = make_ushort4(
            f2h((a1.x - mean) * rstd * gv.x + bv.x),
            f2h((a1.y - mean) * rstd * gv.y + bv.y),
            f2h((a1.z - mean) * rstd * gv.z + bv.z),
            f2h((a1.w - mean) * rstd * gv.w + bv.w));
    }
}

// ---------------- fp16 MFMA GEMM, 128x128 tile, BK=64 ----------------
// A dense fp16 [M][K] (lda in elements); B fp16 [Np][K].
// EPI: 1 = C=acc+bias+R; 2 = gelu -> fp16 Ch; 4 = qkv scatter (Q scaled, K, V^T fp16).
template<int EPI>
__global__ __launch_bounds__(256, 4) void mgemm(
    const u16* __restrict__ A, long lda, const u16* __restrict__ B,
    const float* __restrict__ bias, const float* __restrict__ R,
    float* __restrict__ C, u16* __restrict__ Ch,
    u16* __restrict__ Qo, u16* __restrict__ Ko, u16* __restrict__ Vo,
    int ldc, int N, int K)
{
    __shared__ __align__(16) u16 sm[2][8192];   // A,B tiles: 128 rows x 64 k, chunk-swizzled
    const int tid = threadIdx.x;

    // XCD-bijective swizzle (all grids have nwg % 8 == 0)
    const int gx = gridDim.x;
    const int nwg = gx * (int)gridDim.y;
    const int bid0 = blockIdx.y * gx + blockIdx.x;
    const int cpx = nwg >> 3;
    const int bid = (bid0 & 7) * cpx + (bid0 >> 3);
    const int bn = (bid % gx) * 128;
    const int bm = (bid / gx) * 128;

    const int lrow  = tid & 31;
    const int lhalf = (tid >> 5) & 1;
    const int wid   = tid >> 6;
    const int wr = (wid >> 1) * 64;
    const int wc = (wid & 1) * 64;

    f32x16 acc[2][2];
    #pragma unroll
    for (int mt = 0; mt < 2; ++mt)
        #pragma unroll
        for (int nt = 0; nt < 2; ++nt)
            #pragma unroll
            for (int i = 0; i < 16; ++i) acc[mt][nt][i] = 0.f;

    for (int k0 = 0; k0 < K; k0 += 64) {
        #pragma unroll
        for (int p = 0; p < 4; ++p) {
            const int idx = p * 256 + tid;
            const int r = idx >> 3, pch = idx & 7;
            const int ke = k0 + ((pch ^ r) & 7) * 8;
            __builtin_amdgcn_global_load_lds(A + (size_t)(bm + r) * lda + ke,
                                             &sm[0][idx * 8], 16, 0, 0);
            __builtin_amdgcn_global_load_lds(B + (size_t)(bn + r) * K + ke,
                                             &sm[1][idx * 8], 16, 0, 0);
        }
        __syncthreads();
        #pragma unroll
        for (int kc = 0; kc < 4; ++kc) {
            short8 fa[2], fb[2];
            const int ch = kc * 2 + lhalf;
            #pragma unroll
            for (int mt = 0; mt < 2; ++mt) {
                const int rr = wr + mt * 32 + lrow;
                fa[mt] = *(const short8*)&sm[0][rr * 64 + (((ch ^ rr) & 7) << 3)];
            }
            #pragma unroll
            for (int nt = 0; nt < 2; ++nt) {
                const int rr = wc + nt * 32 + lrow;
                fb[nt] = *(const short8*)&sm[1][rr * 64 + (((ch ^ rr) & 7) << 3)];
            }
            #pragma unroll
            for (int mt = 0; mt < 2; ++mt)
                #pragma unroll
                for (int nt = 0; nt < 2; ++nt)
                    acc[mt][nt] = __builtin_amdgcn_mfma_f32_32x32x16_f16(fa[mt], fb[nt], acc[mt][nt], 0, 0, 0);
        }
        __syncthreads();
    }

    // epilogue: C/D layout col = lane&31, row = (i&3) + 8*(i>>2) + 4*(lane>>5)
    const int bb = bm >> 11;            // batch (block never straddles: 128 | 2048)
    const int sbase = (bm & 2047);
    #pragma unroll
    for (int mt = 0; mt < 2; ++mt) {
        #pragma unroll
        for (int nt = 0; nt < 2; ++nt) {
            const int col = bn + wc + nt * 32 + lrow;
            if (col < N) {
                const float bsv = bias[col];
                if (EPI != 4) {
                    #pragma unroll
                    for (int i = 0; i < 16; ++i) {
                        const int row = bm + wr + mt * 32 + (i & 3) + 8 * (i >> 2) + 4 * lhalf;
                        float v = acc[mt][nt][i] + bsv;
                        const size_t o = (size_t)row * ldc + col;
                        if (EPI == 1) C[o] = v + R[o];
                        else          Ch[o] = f2h(gelu_f(v));
                    }
                } else if (col < 3200) {
                    // Q (scaled) / K: [bh][s][64] fp16
                    const int cr = (col < 1600) ? col : col - 1600;
                    const float scl = (col < 1600) ? 0.125f : 1.0f;
                    u16* P = ((col < 1600) ? Qo : Ko)
                             + (((size_t)(bb * H_ + (cr >> 6))) << 17) + (cr & 63);
                    #pragma unroll
                    for (int i = 0; i < 16; ++i) {
                        const int s = sbase + wr + mt * 32 + (i & 3) + 8 * (i >> 2) + 4 * lhalf;
                        P[(size_t)s << 6] = f2h((acc[mt][nt][i] + bsv) * scl);
                    }
                } else {
                    // V^T: [bh][c][2048] fp16, 4-consecutive-s grouped stores
                    const int cr = col - 3200;
                    u16* P = Vo + (((size_t)(bb * H_ + (cr >> 6))) << 17) + ((size_t)(cr & 63) << 11);
                    #pragma unroll
                    for (int q = 0; q < 4; ++q) {
                        const int s = sbase + wr + mt * 32 + 8 * q + 4 * lhalf;
                        ushort4 hv = make_ushort4(
                            f2h(acc[mt][nt][q * 4 + 0] + bsv), f2h(acc[mt][nt][q * 4 + 1] + bsv),
                            f2h(acc[mt][nt][q * 4 + 2] + bsv), f2h(acc[mt][nt][q * 4 + 3] + bsv));
                        *(ushort4*)(P + s) = hv;
                    }
                }
            }
        }
    }
}

// ---------------- fp16 MFMA flash attention, causal, head dim 64 ----------------
// Inputs: Q16 (pre-scaled) / K16 [bh][2048][64] fp16, V16T [bh][64][2048] fp16.
// All staging via global_load_lds (pre-swizzled source). Output: dense fp16 att[4096][1600].
__global__ __launch_bounds__(256, 3) void attn_mfma(
    const u16* __restrict__ Q16, const u16* __restrict__ K16,
    const u16* __restrict__ V16T, u16* __restrict__ att)
{
    __shared__ __align__(16) u16 Qs[128 * 64];    // 16 KB
    __shared__ __align__(16) u16 Ks[64 * 64];     // 8 KB
    __shared__ __align__(16) u16 Vt[64 * 64];     // 8 KB (c-major: row=c, col=key)
    __shared__ __align__(16) u16 Ps[4][32 * 64];  // 16 KB (per wave, row=qrow, col=key)

    const int tid = threadIdx.x;
    const int lane = tid & 63;
    const int wid = tid >> 6;
    const int l31 = lane & 31;
    const int lh  = lane >> 5;
    const int qi = (int)gridDim.x - 1 - (int)blockIdx.x;   // heavy blocks first
    const int q0 = qi * 128;
    const int bh = blockIdx.y;
    const u16* qb = Q16 + ((size_t)bh << 17);
    const u16* kb = K16 + ((size_t)bh << 17);
    const u16* vb = V16T + ((size_t)bh << 17);

    // ---- stage Q via global_load_lds (pre-swizzled source) ----
    #pragma unroll
    for (int p = 0; p < 4; ++p) {
        const int idx = p * 256 + tid;
        const int r = idx >> 3, pch = idx & 7;
        __builtin_amdgcn_global_load_lds(qb + (size_t)(q0 + r) * 64 + ((pch ^ r) & 7) * 8,
                                         &Qs[idx * 8], 16, 0, 0);
    }
    __syncthreads();

    // ---- hoist this wave's Q fragments (B-operand: col=qrow, k=c) ----
    short8 fq[4];
    const int qrow = wid * 32 + l31;
    #pragma unroll
    for (int m = 0; m < 4; ++m)
        fq[m] = *(const short8*)&Qs[swz(qrow, m * 16 + lh * 8)];

    f32x16 o0, o1;
    #pragma unroll
    for (int i = 0; i < 16; ++i) { o0[i] = 0.f; o1[i] = 0.f; }
    float m_run = -INFINITY, l_run = 0.f;
    const int wq0 = q0 + wid * 32;
    const int myq = wq0 + l31;
    const int ntiles = q0 / 64 + 2;

    for (int t = 0; t < ntiles; ++t) {
        const int k0 = t * 64;
        __syncthreads();   // previous tile's K/V reads complete
        // ---- stage K rows and V^T channel-rows via global_load_lds ----
        #pragma unroll
        for (int p = 0; p < 2; ++p) {
            const int idx = p * 256 + tid;
            const int r = idx >> 3, pch = idx & 7;
            const int c8 = ((pch ^ r) & 7) * 8;
            __builtin_amdgcn_global_load_lds(kb + (size_t)(k0 + r) * 64 + c8,
                                             &Ks[idx * 8], 16, 0, 0);
            __builtin_amdgcn_global_load_lds(vb + ((size_t)r << 11) + k0 + c8,
                                             &Vt[idx * 8], 16, 0, 0);
        }
        __syncthreads();

        if (k0 < wq0 + 32) {   // causal participation for this wave
            // ---- S^T = K . Q^T, two 32-key subtiles ----
            f32x16 s0, s1;
            #pragma unroll
            for (int i = 0; i < 16; ++i) { s0[i] = 0.f; s1[i] = 0.f; }
            #pragma unroll
            for (int m = 0; m < 4; ++m) {
                const int co = m * 16 + lh * 8;
                short8 k0f = *(const short8*)&Ks[swz(l31, co)];
                short8 k1f = *(const short8*)&Ks[swz(32 + l31, co)];
                s0 = __builtin_amdgcn_mfma_f32_32x32x16_f16(k0f, fq[m], s0, 0, 0, 0);
                s1 = __builtin_amdgcn_mfma_f32_32x32x16_f16(k1f, fq[m], s1, 0, 0, 0);
            }

            // ---- causal mask + online softmax (per-lane row = myq) ----
            float smax = -INFINITY;
            #pragma unroll
            for (int i = 0; i < 16; ++i) {
                const int kb2 = (i & 3) + 8 * (i >> 2) + 4 * lh;
                float x0 = (k0 + kb2 > myq) ? -INFINITY : s0[i];
                float x1 = (k0 + 32 + kb2 > myq) ? -INFINITY : s1[i];
                s0[i] = x0; s1[i] = x1;
                smax = fmaxf(smax, fmaxf(x0, x1));
            }
            smax = fmaxf(smax, __shfl_xor(smax, 32));
            const float mn = fmaxf(m_run, smax);
            const float sc = __expf(m_run - mn);
            m_run = mn;
            float ls = 0.f;
            #pragma unroll
            for (int i = 0; i < 16; ++i) {
                const float p0 = __expf(s0[i] - mn);
                const float p1 = __expf(s1[i] - mn);
                s0[i] = p0; s1[i] = p1;
                ls += p0 + p1;
            }
            ls += __shfl_xor(ls, 32);
            l_run = l_run * sc + ls;

            // ---- pack P -> fp16 pairs in per-wave LDS (row=qrow, col=key) ----
            #pragma unroll
            for (int j = 0; j < 8; ++j) {
                const int i = 2 * j;
                const int kb2 = (i & 3) + 8 * (i >> 2) + 4 * lh;
                unsigned pk0 = (unsigned)f2h(s0[i]) | ((unsigned)f2h(s0[i + 1]) << 16);
                unsigned pk1 = (unsigned)f2h(s1[i]) | ((unsigned)f2h(s1[i + 1]) << 16);
                *(unsigned*)&Ps[wid][swz(l31, kb2)]      = pk0;
                *(unsigned*)&Ps[wid][swz(l31, 32 + kb2)] = pk1;
            }

            // ---- rescale O ----
            float scs[16];
            #pragma unroll
            for (int i = 0; i < 16; ++i)
                scs[i] = __shfl(sc, (i & 3) + 8 * (i >> 2) + 4 * lh);
            #pragma unroll
            for (int i = 0; i < 16; ++i) { o0[i] *= scs[i]; o1[i] *= scs[i]; }

            // ---- O += P . V ----
            #pragma unroll
            for (int m = 0; m < 4; ++m) {
                const int co = m * 16 + lh * 8;
                short8 fp  = *(const short8*)&Ps[wid][swz(l31, co)];
                short8 fv0 = *(const short8*)&Vt[swz(l31, co)];
                short8 fv1 = *(const short8*)&Vt[swz(32 + l31, co)];
                o0 = __builtin_amdgcn_mfma_f32_32x32x16_f16(fp, fv0, o0, 0, 0, 0);
                o1 = __builtin_amdgcn_mfma_f32_32x32x16_f16(fp, fv1, o1, 0, 0, 0);
            }
        }
    }

    // ---- normalize + write fp16 to dense att[4096][1600] ----
    const int bb = bh / H_, h = bh % H_;
    const float inv = 1.f / l_run;
    #pragma unroll
    for (int i = 0; i < 16; ++i) {
        const int ri = (i & 3) + 8 * (i >> 2) + 4 * lh;
        const float sci = __shfl(inv, ri);
        u16* ph = att + (size_t)(bb * S_ + q0 + wid * 32 + ri) * D_ + h * 64;
        ph[l31]      = f2h(o0[i] * sci);
        ph[32 + l31] = f2h(o1[i] * sci);
    }
}

extern "C" void kernel_launch(void* const* d_in, const int* in_sizes, int n_in,
                              void* d_out, int out_size, void* d_ws, size_t ws_size,
                              hipStream_t stream) {
    const float* x         = (const float*)d_in[0];
    const float* g1        = (const float*)d_in[1];
    const float* b1        = (const float*)d_in[2];
    const float* w_qkv     = (const float*)d_in[3];
    const float* bias_qkv  = (const float*)d_in[4];
    const float* w_proj    = (const float*)d_in[5];
    const float* bias_proj = (const float*)d_in[6];
    const float* g2        = (const float*)d_in[7];
    const float* b2        = (const float*)d_in[8];
    const float* w_fc      = (const float*)d_in[9];
    const float* bias_fc   = (const float*)d_in[10];
    const float* w_out     = (const float*)d_in[11];
    const float* bias_out  = (const float*)d_in[12];
    float* out = (float*)d_out;
    char* W = (char*)d_ws;

    // workspace layout (bytes), peak 113,049,600 (< 152,371,200 proven safe):
    u16*   xn    = (u16*)  (W + 0);           // 13,107,200  fp16 [4096][1600]
    float* x1    = (float*)(W + 13107200);    // 26,214,400
    u16*   Q16   = (u16*)  (W + 39321600);    // 13,107,200  fp16 [50][2048][64]
    u16*   K16   = (u16*)  (W + 52428800);    // 13,107,200
    u16*   V16T  = (u16*)  (W + 65536000);    // 13,107,200  fp16 [50][64][2048]
    u16*   att16 = (u16*)  (W + 78643200);    // 13,107,200  fp16 [4096][1600]
    u16*   hdn   = (u16*)  (W + 39321600);    // 52,428,800  fp16 [4096][6400] (overlays Q16..att16)
    u16*   wT    = (u16*)  (W + 91750400);    // up to 21,299,200 -> ends 113,049,600

    dim3 blk(256);

    // 1. LN1 -> fp16
    ln_f16_kernel<<<4096, blk, 0, stream>>>(x, g1, b1, xn);

    // 2. qkv GEMM with fp16 Q/K/V^T scatter epilogue (Np=4864)
    wconv_kernel<<<dim3(152, 50), blk, 0, stream>>>(w_qkv, 4800, wT, 1600, 4800);
    mgemm<4><<<dim3(38, 32), blk, 0, stream>>>(
        xn, 1600L, wT, bias_qkv, nullptr, nullptr, nullptr,
        Q16, K16, V16T, 0, 4800, 1600);

    // 3. MFMA flash attention -> dense fp16 att16
    attn_mfma<<<dim3(16, 50), blk, 0, stream>>>(Q16, K16, V16T, att16);

    // 4. x1 = att @ w_proj + bias + x   (Np=1664)
    wconv_kernel<<<dim3(52, 50), blk, 0, stream>>>(w_proj, 1600, wT, 1600, 1600);
    mgemm<1><<<dim3(13, 32), blk, 0, stream>>>(
        att16, 1600L, wT, bias_proj, x, x1, nullptr,
        nullptr, nullptr, nullptr, 1600, 1600, 1600);

    // 5. LN2 -> fp16
    ln_f16_kernel<<<4096, blk, 0, stream>>>(x1, g2, b2, xn);

    // 6. hdn = gelu(xn @ w_fc + bias) -> fp16 (Np=6400)
    wconv_kernel<<<dim3(200, 50), blk, 0, stream>>>(w_fc, 6400, wT, 1600, 6400);
    mgemm<2><<<dim3(50, 32), blk, 0, stream>>>(
        xn, 1600L, wT, bias_fc, nullptr, nullptr, hdn,
        nullptr, nullptr, nullptr, 6400, 6400, 1600);

    // 7. out = hdn @ w_out + bias + x1  (K=6400, Np=1664)
    wconv_kernel<<<dim3(52, 200), blk, 0, stream>>>(w_out, 1600, wT, 6400, 1600);
    mgemm<1><<<dim3(13, 32), blk, 0, stream>>>(
        hdn, 6400L, wT, bias_out, x1, out, nullptr,
        nullptr, nullptr, nullptr, 1600, 1600, 6400);
}